// Round 1
// baseline (416.264 us; speedup 1.0000x reference)
//
#include <hip/hip_runtime.h>

#define HW 4096

// ---------------------------------------------------------------------------
// K1: 3x3 conv + BN(eval) + ReLU for both spatial (s_x) and channel (c_x)
// grid 256 = which(2) x b(2) x ocg(16: 4 oc each) x quarter(4: 16 rows each)
// thread: 4 pixels in one row (w0..w0+3), 4 output channels -> 16 acc regs
// weights are block-uniform -> scalar loads (free FMA operand)
// ---------------------------------------------------------------------------
__global__ __launch_bounds__(256) void k_conv3(
    const float* __restrict__ x,
    const float* __restrict__ sW, const float* __restrict__ sb,
    const float* __restrict__ s_g, const float* __restrict__ s_b,
    const float* __restrict__ s_m, const float* __restrict__ s_v,
    const float* __restrict__ cW, const float* __restrict__ cb,
    const float* __restrict__ c_g, const float* __restrict__ c_b,
    const float* __restrict__ c_m, const float* __restrict__ c_v,
    float* __restrict__ sx, float* __restrict__ cx)
{
    int bx = blockIdx.x;
    int which = bx >> 7;
    int b     = (bx >> 6) & 1;
    int ocg   = (bx >> 2) & 15;
    int qt    = bx & 3;
    const float* W   = which ? cW  : sW;
    const float* cbp = which ? cb  : sb;
    const float* gp  = which ? c_g : s_g;
    const float* bbp = which ? c_b : s_b;
    const float* mp  = which ? c_m : s_m;
    const float* vp  = which ? c_v : s_v;
    float* out = which ? cx : sx;

    int t  = threadIdx.x;
    int r  = qt * 16 + (t >> 4);
    int w0 = (t & 15) * 4;

    float acc[4][4];
#pragma unroll
    for (int i = 0; i < 4; i++)
#pragma unroll
        for (int p = 0; p < 4; p++) acc[i][p] = 0.f;

    // validity / clamped indices (ic-invariant)
    int  idx[3][6];
    bool ok [3][6];
#pragma unroll
    for (int kh = 0; kh < 3; kh++) {
        int hh = r + kh - 1;
        bool rok = (hh >= 0) && (hh < 64);
#pragma unroll
        for (int j = 0; j < 6; j++) {
            int ww = w0 + j - 1;
            bool cok = (ww >= 0) && (ww < 64);
            ok[kh][j]  = rok && cok;
            idx[kh][j] = ok[kh][j] ? (hh * 64 + ww) : 0;
        }
    }

    const float* xb = x + (size_t)(b * 64) * HW;
    for (int ic = 0; ic < 64; ic++) {
        const float* xpl = xb + ic * HW;
        float xr[3][6];
#pragma unroll
        for (int kh = 0; kh < 3; kh++)
#pragma unroll
            for (int j = 0; j < 6; j++) {
                float v = xpl[idx[kh][j]];
                xr[kh][j] = ok[kh][j] ? v : 0.f;
            }
#pragma unroll
        for (int oc = 0; oc < 4; oc++) {
            const float* wp = W + (size_t)((ocg * 4 + oc) * 64 + ic) * 9;
#pragma unroll
            for (int kh = 0; kh < 3; kh++)
#pragma unroll
                for (int kw = 0; kw < 3; kw++) {
                    float wv = wp[kh * 3 + kw];
#pragma unroll
                    for (int p = 0; p < 4; p++)
                        acc[oc][p] += wv * xr[kh][p + kw];
                }
        }
    }

#pragma unroll
    for (int oc = 0; oc < 4; oc++) {
        int och = ocg * 4 + oc;
        float scale = gp[och] * rsqrtf(vp[och] + 1e-5f);
        float shift = bbp[och] - mp[och] * scale;
        float* op = out + (size_t)(b * 64 + och) * HW + r * 64 + w0;
#pragma unroll
        for (int p = 0; p < 4; p++) {
            float y = (acc[oc][p] + cbp[och]) * scale + shift;
            op[p] = fmaxf(y, 0.f);
        }
    }
}

// ---------------------------------------------------------------------------
// K2: 1x1 convs q,k,v. Outputs: q [B][8][HW] (d-major), kT [B][HW][8],
// vT [B][HW][64] (transposed so the attention kernel stages coalesced).
// grid 160 = b(2) x chunk(16) x g(5: 16 out-channels each; g=0 -> q+k)
// ---------------------------------------------------------------------------
__global__ __launch_bounds__(256) void k_qkv(
    const float* __restrict__ x,
    const float* __restrict__ qW, const float* __restrict__ qb,
    const float* __restrict__ kW, const float* __restrict__ kb,
    const float* __restrict__ vW, const float* __restrict__ vb,
    float* __restrict__ q, float* __restrict__ kT, float* __restrict__ vT)
{
    int bx = blockIdx.x;
    int b = bx / 80, rem = bx % 80;
    int chunk = rem / 5, g = rem % 5;
    int t  = threadIdx.x;
    int hw = chunk * 256 + t;
    const float* xb = x + (size_t)(b * 64) * HW + hw;

    float acc[16];
#pragma unroll
    for (int u = 0; u < 16; u++) acc[u] = 0.f;

    if (g == 0) {
        for (int ic = 0; ic < 64; ic++) {
            float xv = xb[ic * HW];
#pragma unroll
            for (int u = 0; u < 8; u++) acc[u]     += qW[u * 64 + ic] * xv;
#pragma unroll
            for (int u = 0; u < 8; u++) acc[8 + u] += kW[u * 64 + ic] * xv;
        }
#pragma unroll
        for (int u = 0; u < 8; u++) q[(size_t)(b * 8 + u) * HW + hw] = acc[u] + qb[u];
#pragma unroll
        for (int u = 0; u < 8; u++) kT[(size_t)(b * HW + hw) * 8 + u] = acc[8 + u] + kb[u];
    } else {
        int c0 = (g - 1) * 16;
        for (int ic = 0; ic < 64; ic++) {
            float xv = xb[ic * HW];
#pragma unroll
            for (int u = 0; u < 16; u++) acc[u] += vW[(c0 + u) * 64 + ic] * xv;
        }
#pragma unroll
        for (int u = 0; u < 16; u++)
            vT[(size_t)(b * HW + hw) * 64 + c0 + u] = acc[u] + vb[c0 + u];
    }
}

// ---------------------------------------------------------------------------
// K3: spatial flash attention (no max-subtraction: |scores| <= ~3 so exp is
// safe). 32 queries/block, j-tiles of 128. fused = s_gamma*sa + s_x.
// score role: (qi = t&31, sg = t>>5): 16 scores each.
// acc role:   (cg = t&15 -> 4 channels, qg = t>>4 -> 2 queries): 8 acc regs,
//             per j: one b64 (P) + one b128 (V) LDS read for 8 FMAs.
// ---------------------------------------------------------------------------
#define TQ 32
#define TJ 128
__global__ __launch_bounds__(256) void k_attn(
    const float* __restrict__ q, const float* __restrict__ kT,
    const float* __restrict__ vT, const float* __restrict__ sx,
    const float* __restrict__ s_gamma, float* __restrict__ fused)
{
    __shared__ float ks[TJ][8];
    __shared__ float vs[TJ][68];
    __shared__ float S [TJ][36];
    __shared__ float den[8][32];

    int t  = threadIdx.x;
    int b  = blockIdx.x >> 7;
    int i0 = (blockIdx.x & 127) * TQ;

    int qi = t & 31, sg = t >> 5;          // score role
    int cg = t & 15, qg = t >> 4;          // acc role
    int c0 = cg * 4, qi0 = qg * 2;

    float qr[8];
#pragma unroll
    for (int d = 0; d < 8; d++) qr[d] = q[(size_t)(b * 8 + d) * HW + i0 + qi];

    float accr[2][4] = {};
    float denr = 0.f;

    const float* kTb = kT + (size_t)b * HW * 8;
    const float* vTb = vT + (size_t)b * HW * 64;

    for (int tile = 0; tile < HW / TJ; tile++) {
        int j0 = tile * TJ;
        // stage K tile (1024 floats)
        {
            int j = t >> 1, d4 = (t & 1) * 4;
            float4 kv = *(const float4*)(kTb + (size_t)(j0 + j) * 8 + d4);
            *(float4*)&ks[j][d4] = kv;
        }
        // stage V tile (8192 floats, 8 float4/thread, bank-balanced)
#pragma unroll
        for (int rr = 0; rr < 8; rr++) {
            int idx = t + 256 * rr;
            int j = idx >> 4, c4 = (idx & 15) * 4;
            float4 vv4 = *(const float4*)(vTb + (size_t)(j0 + j) * 64 + c4);
            *(float4*)&vs[j][c4] = vv4;
        }
        __syncthreads();

        // scores -> exp -> S[j][qi], denominator partial in reg
#pragma unroll
        for (int jj = 0; jj < 16; jj++) {
            int j = sg * 16 + jj;
            float4 k0 = *(const float4*)&ks[j][0];
            float4 k1 = *(const float4*)&ks[j][4];
            float s = qr[0]*k0.x + qr[1]*k0.y + qr[2]*k0.z + qr[3]*k0.w
                    + qr[4]*k1.x + qr[5]*k1.y + qr[6]*k1.z + qr[7]*k1.w;
            float p = __expf(s);
            denr += p;
            S[j][qi] = p;
        }
        __syncthreads();

        // accumulate P*V
#pragma unroll 4
        for (int j = 0; j < TJ; j++) {
            float2 p2 = *(const float2*)&S[j][qi0];
            float4 v4 = *(const float4*)&vs[j][c0];
            accr[0][0] += p2.x * v4.x; accr[0][1] += p2.x * v4.y;
            accr[0][2] += p2.x * v4.z; accr[0][3] += p2.x * v4.w;
            accr[1][0] += p2.y * v4.x; accr[1][1] += p2.y * v4.y;
            accr[1][2] += p2.y * v4.z; accr[1][3] += p2.y * v4.w;
        }
        __syncthreads();
    }

    den[sg][qi] = denr;
    __syncthreads();

    float sgam = s_gamma[0];
#pragma unroll
    for (int u = 0; u < 2; u++) {
        float ds = 0.f;
#pragma unroll
        for (int gg = 0; gg < 8; gg++) ds += den[gg][qi0 + u];
        float inv = 1.f / ds;
        int i = i0 + qi0 + u;
#pragma unroll
        for (int w = 0; w < 4; w++) {
            int c = c0 + w;
            size_t o = (size_t)(b * 64 + c) * HW + i;
            fused[o] = sgam * (accr[u][w] * inv) + sx[o];
        }
    }
}

// ---------------------------------------------------------------------------
// K4a: channel gram Ac[b,i,j] = sum_hw cx[i,hw]*cx[j,hw], hw-sliced blocks,
// fp32 atomics into Ac. grid 256 = b(2) x igroup(16: 4 rows) x slice(8: 512hw)
// ---------------------------------------------------------------------------
__global__ __launch_bounds__(256) void k_gram(
    const float* __restrict__ cx, float* __restrict__ Ac)
{
    int bx = blockIdx.x;
    int b = bx >> 7, rem = bx & 127;
    int ig = rem >> 3, sl = rem & 7;
    int i0 = ig * 4, hw0 = sl * 512;
    int t = threadIdx.x;
    int irow = t >> 6, l = t & 63;

    const float* cxb = cx + (size_t)(b * 64) * HW;
    const float* xip = cxb + (size_t)(i0 + irow) * HW + hw0 + l;

    float acc[64];
#pragma unroll
    for (int j = 0; j < 64; j++) acc[j] = 0.f;

    for (int it = 0; it < 8; it++) {
        int off = it * 64;
        float xv = xip[off];
        const float* base = cxb + hw0 + l + off;
#pragma unroll
        for (int j = 0; j < 64; j++)
            acc[j] += base[(size_t)j * HW] * xv;
    }

    // butterfly-reduce each acc[j] across the wave; lane j commits j
    float sel = 0.f;
#pragma unroll
    for (int j = 0; j < 64; j++) {
        float v = acc[j];
        v += __shfl_xor(v, 1);
        v += __shfl_xor(v, 2);
        v += __shfl_xor(v, 4);
        v += __shfl_xor(v, 8);
        v += __shfl_xor(v, 16);
        v += __shfl_xor(v, 32);
        sel = (l == j) ? v : sel;
    }
    atomicAdd(&Ac[(size_t)(b * 64 + i0 + irow) * 64 + l], sel);
}

// ---------------------------------------------------------------------------
// K4b: row softmax of (min-trick): softmax(max_j(A)-A) == exp(amin-a)/sum.
// Writes transposed AcsT[b][j][i]. grid 128 rows, 64 threads (1 wave).
// ---------------------------------------------------------------------------
__global__ __launch_bounds__(64) void k_csoft(
    const float* __restrict__ Ac, float* __restrict__ AcsT)
{
    int row = blockIdx.x;
    int b = row >> 6, i = row & 63;
    int j = threadIdx.x;
    float a = Ac[(size_t)(b * 64 + i) * 64 + j];
    float mn = a;
    mn = fminf(mn, __shfl_xor(mn, 1));
    mn = fminf(mn, __shfl_xor(mn, 2));
    mn = fminf(mn, __shfl_xor(mn, 4));
    mn = fminf(mn, __shfl_xor(mn, 8));
    mn = fminf(mn, __shfl_xor(mn, 16));
    mn = fminf(mn, __shfl_xor(mn, 32));
    float p = __expf(mn - a);
    float s = p;
    s += __shfl_xor(s, 1);
    s += __shfl_xor(s, 2);
    s += __shfl_xor(s, 4);
    s += __shfl_xor(s, 8);
    s += __shfl_xor(s, 16);
    s += __shfl_xor(s, 32);
    AcsT[(size_t)b * 4096 + j * 64 + i] = p / s;
}

// ---------------------------------------------------------------------------
// K5: ca = AcsT^T @ cx ; fused += c_gamma*ca + cx
// grid 128 = b(2) x chunk(16) x cgroup(4: 16 channels)
// ---------------------------------------------------------------------------
__global__ __launch_bounds__(256) void k_chapply(
    const float* __restrict__ cx, const float* __restrict__ AcsT,
    const float* __restrict__ c_gamma, float* __restrict__ fused)
{
    __shared__ float asl[64][68];
    int bx = blockIdx.x;
    int b = bx >> 6, rem = bx & 63;
    int chunk = rem >> 2, cgp = rem & 3;
    int i0 = cgp * 16;
    int t = threadIdx.x;
    int hw = chunk * 256 + t;

#pragma unroll
    for (int rr = 0; rr < 16; rr++) {
        int idx = t + 256 * rr;
        int j = idx >> 6, i = idx & 63;
        asl[j][i] = AcsT[(size_t)b * 4096 + idx];
    }
    __syncthreads();

    const float* cxb = cx + (size_t)(b * 64) * HW + hw;
    float acc[16] = {};
    for (int j = 0; j < 64; j++) {
        float xv = cxb[(size_t)j * HW];
        float4 a0 = *(const float4*)&asl[j][i0];
        float4 a1 = *(const float4*)&asl[j][i0 + 4];
        float4 a2 = *(const float4*)&asl[j][i0 + 8];
        float4 a3 = *(const float4*)&asl[j][i0 + 12];
        acc[0]  += a0.x * xv; acc[1]  += a0.y * xv; acc[2]  += a0.z * xv; acc[3]  += a0.w * xv;
        acc[4]  += a1.x * xv; acc[5]  += a1.y * xv; acc[6]  += a1.z * xv; acc[7]  += a1.w * xv;
        acc[8]  += a2.x * xv; acc[9]  += a2.y * xv; acc[10] += a2.z * xv; acc[11] += a2.w * xv;
        acc[12] += a3.x * xv; acc[13] += a3.y * xv; acc[14] += a3.z * xv; acc[15] += a3.w * xv;
    }

    float cgam = c_gamma[0];
#pragma unroll
    for (int u = 0; u < 16; u++) {
        int i = i0 + u;
        size_t o = (size_t)(b * 64 + i) * HW + hw;
        fused[o] = fused[o] + cgam * acc[u] + cx[(size_t)(b * 64 + i) * HW + hw];
    }
}

// ---------------------------------------------------------------------------
// K6: out = oW @ fused + ob. grid 128 = b(2) x chunk(16) x ogroup(4)
// ---------------------------------------------------------------------------
__global__ __launch_bounds__(256) void k_outconv(
    const float* __restrict__ fused, const float* __restrict__ oW,
    const float* __restrict__ ob, float* __restrict__ out)
{
    int bx = blockIdx.x;
    int b = bx >> 6, rem = bx & 63;
    int chunk = rem >> 2, og = rem & 3;
    int o0 = og * 16;
    int t = threadIdx.x;
    int hw = chunk * 256 + t;

    const float* fb = fused + (size_t)(b * 64) * HW + hw;
    float acc[16] = {};
    for (int c = 0; c < 64; c++) {
        float fv = fb[(size_t)c * HW];
#pragma unroll
        for (int u = 0; u < 16; u++)
            acc[u] += oW[(o0 + u) * 64 + c] * fv;
    }
#pragma unroll
    for (int u = 0; u < 16; u++)
        out[(size_t)(b * 64 + o0 + u) * HW + hw] = acc[u] + ob[o0 + u];
}

// ---------------------------------------------------------------------------
extern "C" void kernel_launch(void* const* d_in, const int* in_sizes, int n_in,
                              void* d_out, int out_size, void* d_ws, size_t ws_size,
                              hipStream_t stream)
{
    const float* x    = (const float*)d_in[0];
    const float* sW   = (const float*)d_in[1];
    const float* sb   = (const float*)d_in[2];
    const float* s_g  = (const float*)d_in[3];
    const float* s_b  = (const float*)d_in[4];
    const float* s_m  = (const float*)d_in[5];
    const float* s_v  = (const float*)d_in[6];
    const float* cW   = (const float*)d_in[7];
    const float* cb   = (const float*)d_in[8];
    const float* c_g  = (const float*)d_in[9];
    const float* c_b  = (const float*)d_in[10];
    const float* c_m  = (const float*)d_in[11];
    const float* c_v  = (const float*)d_in[12];
    const float* qW   = (const float*)d_in[13];
    const float* qb   = (const float*)d_in[14];
    const float* kW   = (const float*)d_in[15];
    const float* kb   = (const float*)d_in[16];
    const float* vW   = (const float*)d_in[17];
    const float* vb   = (const float*)d_in[18];
    const float* oW   = (const float*)d_in[19];
    const float* ob   = (const float*)d_in[20];
    const float* s_gamma = (const float*)d_in[21];
    const float* c_gamma = (const float*)d_in[22];

    float* ws    = (float*)d_ws;
    float* sx    = ws;                 // 524288
    float* cx    = ws + 524288;        // 524288
    float* qbuf  = ws + 1048576;       // 65536   [B][8][HW]
    float* kT    = ws + 1114112;       // 65536   [B][HW][8]
    float* vT    = ws + 1179648;       // 524288  [B][HW][64]
    float* fused = ws + 1703936;       // 524288
    float* AcsT  = ws + 2228224;       // 8192    [B][64j][64i]
    float* Ac    = ws + 2236416;       // 8192    [B][64i][64j]

    hipMemsetAsync(Ac, 0, 2 * 64 * 64 * sizeof(float), stream);

    k_conv3<<<256, 256, 0, stream>>>(x, sW, sb, s_g, s_b, s_m, s_v,
                                     cW, cb, c_g, c_b, c_m, c_v, sx, cx);
    k_qkv<<<160, 256, 0, stream>>>(x, qW, qb, kW, kb, vW, vb, qbuf, kT, vT);
    k_gram<<<256, 256, 0, stream>>>(cx, Ac);
    k_csoft<<<128, 64, 0, stream>>>(Ac, AcsT);
    k_attn<<<256, 256, 0, stream>>>(qbuf, kT, vT, sx, s_gamma, fused);
    k_chapply<<<128, 256, 0, stream>>>(cx, AcsT, c_gamma, fused);
    k_outconv<<<128, 256, 0, stream>>>(fused, oW, ob, (float*)d_out);
}

// Round 2
// 346.736 us; speedup vs baseline: 1.2005x; 1.2005x over previous
//
#include <hip/hip_runtime.h>

#define HW 4096

typedef __attribute__((ext_vector_type(8)))  short short8;
typedef __attribute__((ext_vector_type(16))) float float16;

__device__ __forceinline__ unsigned short f2bf(float f) {
    unsigned u = __float_as_uint(f);
    u += 0x7fffu + ((u >> 16) & 1u);   // RNE
    return (unsigned short)(u >> 16);
}

// ---------------------------------------------------------------------------
// K1: 3x3 conv + BN(eval) + ReLU for both spatial (s_x) and channel (c_x)
// grid 512 = which(2) x b(2) x ocg(32: 2 oc each) x quarter(4: 16 rows each)
// ---------------------------------------------------------------------------
__global__ __launch_bounds__(256) void k_conv3(
    const float* __restrict__ x,
    const float* __restrict__ sW, const float* __restrict__ sb,
    const float* __restrict__ s_g, const float* __restrict__ s_b,
    const float* __restrict__ s_m, const float* __restrict__ s_v,
    const float* __restrict__ cW, const float* __restrict__ cb,
    const float* __restrict__ c_g, const float* __restrict__ c_b,
    const float* __restrict__ c_m, const float* __restrict__ c_v,
    float* __restrict__ sx, float* __restrict__ cx)
{
    int bx = blockIdx.x;
    int which = bx >> 8;
    int b     = (bx >> 7) & 1;
    int ocg   = (bx >> 2) & 31;
    int qt    = bx & 3;
    const float* W   = which ? cW  : sW;
    const float* cbp = which ? cb  : sb;
    const float* gp  = which ? c_g : s_g;
    const float* bbp = which ? c_b : s_b;
    const float* mp  = which ? c_m : s_m;
    const float* vp  = which ? c_v : s_v;
    float* out = which ? cx : sx;

    int t  = threadIdx.x;
    int r  = qt * 16 + (t >> 4);
    int w0 = (t & 15) * 4;

    float acc[2][4];
#pragma unroll
    for (int i = 0; i < 2; i++)
#pragma unroll
        for (int p = 0; p < 4; p++) acc[i][p] = 0.f;

    int  idx[3][6];
    bool ok [3][6];
#pragma unroll
    for (int kh = 0; kh < 3; kh++) {
        int hh = r + kh - 1;
        bool rok = (hh >= 0) && (hh < 64);
#pragma unroll
        for (int j = 0; j < 6; j++) {
            int ww = w0 + j - 1;
            bool cok = (ww >= 0) && (ww < 64);
            ok[kh][j]  = rok && cok;
            idx[kh][j] = ok[kh][j] ? (hh * 64 + ww) : 0;
        }
    }

    const float* xb = x + (size_t)(b * 64) * HW;
    for (int ic = 0; ic < 64; ic++) {
        const float* xpl = xb + ic * HW;
        float xr[3][6];
#pragma unroll
        for (int kh = 0; kh < 3; kh++)
#pragma unroll
            for (int j = 0; j < 6; j++) {
                float v = xpl[idx[kh][j]];
                xr[kh][j] = ok[kh][j] ? v : 0.f;
            }
#pragma unroll
        for (int oc = 0; oc < 2; oc++) {
            const float* wp = W + (size_t)((ocg * 2 + oc) * 64 + ic) * 9;
#pragma unroll
            for (int kh = 0; kh < 3; kh++)
#pragma unroll
                for (int kw = 0; kw < 3; kw++) {
                    float wv = wp[kh * 3 + kw];
#pragma unroll
                    for (int p = 0; p < 4; p++)
                        acc[oc][p] += wv * xr[kh][p + kw];
                }
        }
    }

#pragma unroll
    for (int oc = 0; oc < 2; oc++) {
        int och = ocg * 2 + oc;
        float scale = gp[och] * rsqrtf(vp[och] + 1e-5f);
        float shift = bbp[och] - mp[och] * scale;
        float* op = out + (size_t)(b * 64 + och) * HW + r * 64 + w0;
#pragma unroll
        for (int p = 0; p < 4; p++) {
            float y = (acc[oc][p] + cbp[och]) * scale + shift;
            op[p] = fmaxf(y, 0.f);
        }
    }
}

// ---------------------------------------------------------------------------
// K2: 1x1 convs q,k,v -> bf16 MFMA-ready layouts:
//   qT[b][hw][8] bf16 (16B rows), kT[b][hw][8] bf16,
//   vS[b][c][hw'] bf16 where hw' swizzles j within each 16-group:
//   m=hw&15 -> (m&3)|((m&4)<<1)|((m&8)>>1)  (swaps blocks 4-7 <-> 8-11)
//   so that the attention kernel's in-register P values (S^T C-layout) are a
//   legal MFMA A-operand with matching k-slot order.
// grid 160 = b(2) x chunk(16) x g(5: g=0 -> q+k, g>=1 -> 16 v-channels)
// ---------------------------------------------------------------------------
__global__ __launch_bounds__(256) void k_qkv(
    const float* __restrict__ x,
    const float* __restrict__ qW, const float* __restrict__ qb,
    const float* __restrict__ kW, const float* __restrict__ kb,
    const float* __restrict__ vW, const float* __restrict__ vb,
    unsigned short* __restrict__ qT, unsigned short* __restrict__ kT,
    unsigned short* __restrict__ vS)
{
    int bx = blockIdx.x;
    int b = bx / 80, rem = bx % 80;
    int chunk = rem / 5, g = rem % 5;
    int t  = threadIdx.x;
    int hw = chunk * 256 + t;
    const float* xb = x + (size_t)(b * 64) * HW + hw;

    float acc[16];
#pragma unroll
    for (int u = 0; u < 16; u++) acc[u] = 0.f;

    if (g == 0) {
        for (int ic = 0; ic < 64; ic++) {
            float xv = xb[ic * HW];
#pragma unroll
            for (int u = 0; u < 8; u++) acc[u]     += qW[u * 64 + ic] * xv;
#pragma unroll
            for (int u = 0; u < 8; u++) acc[8 + u] += kW[u * 64 + ic] * xv;
        }
        short8 qv, kv;
#pragma unroll
        for (int u = 0; u < 8; u++) qv[u] = (short)f2bf(acc[u] + qb[u]);
#pragma unroll
        for (int u = 0; u < 8; u++) kv[u] = (short)f2bf(acc[8 + u] + kb[u]);
        *(short8*)(qT + ((size_t)(b * HW) + hw) * 8) = qv;
        *(short8*)(kT + ((size_t)(b * HW) + hw) * 8) = kv;
    } else {
        int c0 = (g - 1) * 16;
        for (int ic = 0; ic < 64; ic++) {
            float xv = xb[ic * HW];
#pragma unroll
            for (int u = 0; u < 16; u++) acc[u] += vW[(c0 + u) * 64 + ic] * xv;
        }
        int m  = hw & 15;
        int jp = (hw & ~15) | (m & 3) | ((m & 4) << 1) | ((m & 8) >> 1);
#pragma unroll
        for (int u = 0; u < 16; u++)
            vS[((size_t)(b * 64) + c0 + u) * HW + jp] = f2bf(acc[u] + vb[c0 + u]);
    }
}

// ---------------------------------------------------------------------------
// K3: spatial flash attention, bf16 MFMA (32x32x16), no P transpose needed:
// S^T-tile = mfma(A=K-frag, B=Q-frag) -> lane holds 16 j's of ONE query i
// (col=lane&31). exp in regs; den = per-lane add. P regs feed PV MFMA directly
// as A-operand (k-slot order absorbed into vS swizzle). 4 waves split j 4-way;
// LDS combine + normalize + fuse with sx.  grid 256 = b(2) x itile(128).
// ---------------------------------------------------------------------------
__global__ __launch_bounds__(256) void k_attn_mfma(
    const unsigned short* __restrict__ qT, const unsigned short* __restrict__ kT,
    const unsigned short* __restrict__ vS, const float* __restrict__ sx,
    const float* __restrict__ s_gamma, float* __restrict__ fused)
{
    __shared__ float o_sh[4][64][33];
    __shared__ float den_sh[4][32];

    int t = threadIdx.x;
    int lane = t & 63, w = t >> 6;
    int half = lane >> 5, l31 = lane & 31;
    int b  = blockIdx.x >> 7;
    int i0 = (blockIdx.x & 127) * 32;

    // Q fragment (B operand): k-slots 8..15 (upper lanes) are the d-pad -> 0
    short8 qf;
    if (half == 0) {
        qf = *(const short8*)(qT + ((size_t)(b * HW) + i0 + l31) * 8);
    } else {
#pragma unroll
        for (int i = 0; i < 8; i++) qf[i] = 0;
    }

    float16 o0, o1;
#pragma unroll
    for (int i = 0; i < 16; i++) { o0[i] = 0.f; o1[i] = 0.f; }
    float denr = 0.f;

    const unsigned short* kTb = kT + (size_t)(b * HW) * 8;
    const unsigned short* vr0 = vS + ((size_t)(b * 64) + l31) * HW;
    const unsigned short* vr1 = vS + ((size_t)(b * 64) + 32 + l31) * HW;

    for (int tile = 0; tile < 32; tile++) {
        int j0 = w * 1024 + tile * 32;

        short8 kf;
        if (half == 0) {
            kf = *(const short8*)(kTb + (size_t)(j0 + l31) * 8);
        } else {
#pragma unroll
            for (int i = 0; i < 8; i++) kf[i] = 0;
        }

        float16 z;
#pragma unroll
        for (int i = 0; i < 16; i++) z[i] = 0.f;
        // S^T tile: D[j_loc][i_loc]; lane: col=i (l31), regs r -> j_loc
        float16 s = __builtin_amdgcn_mfma_f32_32x32x16_bf16(kf, qf, z, 0, 0, 0);

        float p[16];
#pragma unroll
        for (int r = 0; r < 16; r++) {
            p[r] = __expf(s[r]);
            denr += p[r];
        }
        short8 pa0, pa1;
#pragma unroll
        for (int r = 0; r < 8; r++) {
            pa0[r] = (short)f2bf(p[r]);
            pa1[r] = (short)f2bf(p[8 + r]);
        }

        int off = j0 + half * 8;
        short8 v00 = *(const short8*)(vr0 + off);
        short8 v01 = *(const short8*)(vr1 + off);
        short8 v10 = *(const short8*)(vr0 + off + 16);
        short8 v11 = *(const short8*)(vr1 + off + 16);

        o0 = __builtin_amdgcn_mfma_f32_32x32x16_bf16(pa0, v00, o0, 0, 0, 0);
        o1 = __builtin_amdgcn_mfma_f32_32x32x16_bf16(pa0, v01, o1, 0, 0, 0);
        o0 = __builtin_amdgcn_mfma_f32_32x32x16_bf16(pa1, v10, o0, 0, 0, 0);
        o1 = __builtin_amdgcn_mfma_f32_32x32x16_bf16(pa1, v11, o1, 0, 0, 0);
    }

    // den: halves cover disjoint j for the same i -> one cross-half add
    float dfull = denr + __shfl_xor(denr, 32);
    if (half == 0) den_sh[w][l31] = dfull;
#pragma unroll
    for (int r = 0; r < 16; r++) {
        int il = (r & 3) + 8 * (r >> 2) + 4 * half;   // i_loc of this reg
        o_sh[w][l31][il]      = o0[r];
        o_sh[w][32 + l31][il] = o1[r];
    }
    __syncthreads();

    int i  = t & 31;
    int cg = t >> 5;
    float dtot = den_sh[0][i] + den_sh[1][i] + den_sh[2][i] + den_sh[3][i];
    float inv  = s_gamma[0] / dtot;
#pragma unroll
    for (int u = 0; u < 8; u++) {
        int c = cg * 8 + u;
        float sv = o_sh[0][c][i] + o_sh[1][c][i] + o_sh[2][c][i] + o_sh[3][c][i];
        size_t off = (size_t)(b * 64 + c) * HW + i0 + i;
        fused[off] = sv * inv + sx[off];
    }
}

// ---------------------------------------------------------------------------
// K4a: channel gram Ac[b,i,j] = sum_hw cx[i,hw]*cx[j,hw]
// ---------------------------------------------------------------------------
__global__ __launch_bounds__(256) void k_gram(
    const float* __restrict__ cx, float* __restrict__ Ac)
{
    int bx = blockIdx.x;
    int b = bx >> 7, rem = bx & 127;
    int ig = rem >> 3, sl = rem & 7;
    int i0 = ig * 4, hw0 = sl * 512;
    int t = threadIdx.x;
    int irow = t >> 6, l = t & 63;

    const float* cxb = cx + (size_t)(b * 64) * HW;
    const float* xip = cxb + (size_t)(i0 + irow) * HW + hw0 + l;

    float acc[64];
#pragma unroll
    for (int j = 0; j < 64; j++) acc[j] = 0.f;

    for (int it = 0; it < 8; it++) {
        int off = it * 64;
        float xv = xip[off];
        const float* base = cxb + hw0 + l + off;
#pragma unroll
        for (int j = 0; j < 64; j++)
            acc[j] += base[(size_t)j * HW] * xv;
    }

    float sel = 0.f;
#pragma unroll
    for (int j = 0; j < 64; j++) {
        float v = acc[j];
        v += __shfl_xor(v, 1);
        v += __shfl_xor(v, 2);
        v += __shfl_xor(v, 4);
        v += __shfl_xor(v, 8);
        v += __shfl_xor(v, 16);
        v += __shfl_xor(v, 32);
        sel = (l == j) ? v : sel;
    }
    atomicAdd(&Ac[(size_t)(b * 64 + i0 + irow) * 64 + l], sel);
}

// ---------------------------------------------------------------------------
// K4b: row softmax of (max - A) via min-trick; writes transposed AcsT[b][j][i]
// ---------------------------------------------------------------------------
__global__ __launch_bounds__(64) void k_csoft(
    const float* __restrict__ Ac, float* __restrict__ AcsT)
{
    int row = blockIdx.x;
    int b = row >> 6, i = row & 63;
    int j = threadIdx.x;
    float a = Ac[(size_t)(b * 64 + i) * 64 + j];
    float mn = a;
    mn = fminf(mn, __shfl_xor(mn, 1));
    mn = fminf(mn, __shfl_xor(mn, 2));
    mn = fminf(mn, __shfl_xor(mn, 4));
    mn = fminf(mn, __shfl_xor(mn, 8));
    mn = fminf(mn, __shfl_xor(mn, 16));
    mn = fminf(mn, __shfl_xor(mn, 32));
    float p = __expf(mn - a);
    float s = p;
    s += __shfl_xor(s, 1);
    s += __shfl_xor(s, 2);
    s += __shfl_xor(s, 4);
    s += __shfl_xor(s, 8);
    s += __shfl_xor(s, 16);
    s += __shfl_xor(s, 32);
    AcsT[(size_t)b * 4096 + j * 64 + i] = p / s;
}

// ---------------------------------------------------------------------------
// K5: ca = AcsT^T @ cx ; fused += c_gamma*ca + cx
// ---------------------------------------------------------------------------
__global__ __launch_bounds__(256) void k_chapply(
    const float* __restrict__ cx, const float* __restrict__ AcsT,
    const float* __restrict__ c_gamma, float* __restrict__ fused)
{
    __shared__ float asl[64][68];
    int bx = blockIdx.x;
    int b = bx >> 6, rem = bx & 63;
    int chunk = rem >> 2, cgp = rem & 3;
    int i0 = cgp * 16;
    int t = threadIdx.x;
    int hw = chunk * 256 + t;

#pragma unroll
    for (int rr = 0; rr < 16; rr++) {
        int idx = t + 256 * rr;
        int j = idx >> 6, i = idx & 63;
        asl[j][i] = AcsT[(size_t)b * 4096 + idx];
    }
    __syncthreads();

    const float* cxb = cx + (size_t)(b * 64) * HW + hw;
    float acc[16] = {};
    for (int j = 0; j < 64; j++) {
        float xv = cxb[(size_t)j * HW];
        float4 a0 = *(const float4*)&asl[j][i0];
        float4 a1 = *(const float4*)&asl[j][i0 + 4];
        float4 a2 = *(const float4*)&asl[j][i0 + 8];
        float4 a3 = *(const float4*)&asl[j][i0 + 12];
        acc[0]  += a0.x * xv; acc[1]  += a0.y * xv; acc[2]  += a0.z * xv; acc[3]  += a0.w * xv;
        acc[4]  += a1.x * xv; acc[5]  += a1.y * xv; acc[6]  += a1.z * xv; acc[7]  += a1.w * xv;
        acc[8]  += a2.x * xv; acc[9]  += a2.y * xv; acc[10] += a2.z * xv; acc[11] += a2.w * xv;
        acc[12] += a3.x * xv; acc[13] += a3.y * xv; acc[14] += a3.z * xv; acc[15] += a3.w * xv;
    }

    float cgam = c_gamma[0];
#pragma unroll
    for (int u = 0; u < 16; u++) {
        int i = i0 + u;
        size_t o = (size_t)(b * 64 + i) * HW + hw;
        fused[o] = fused[o] + cgam * acc[u] + cx[(size_t)(b * 64 + i) * HW + hw];
    }
}

// ---------------------------------------------------------------------------
// K6: out = oW @ fused + ob
// ---------------------------------------------------------------------------
__global__ __launch_bounds__(256) void k_outconv(
    const float* __restrict__ fused, const float* __restrict__ oW,
    const float* __restrict__ ob, float* __restrict__ out)
{
    int bx = blockIdx.x;
    int b = bx >> 6, rem = bx & 63;
    int chunk = rem >> 2, og = rem & 3;
    int o0 = og * 16;
    int t = threadIdx.x;
    int hw = chunk * 256 + t;

    const float* fb = fused + (size_t)(b * 64) * HW + hw;
    float acc[16] = {};
    for (int c = 0; c < 64; c++) {
        float fv = fb[(size_t)c * HW];
#pragma unroll
        for (int u = 0; u < 16; u++)
            acc[u] += oW[(o0 + u) * 64 + c] * fv;
    }
#pragma unroll
    for (int u = 0; u < 16; u++)
        out[(size_t)(b * 64 + o0 + u) * HW + hw] = acc[u] + ob[o0 + u];
}

// ---------------------------------------------------------------------------
extern "C" void kernel_launch(void* const* d_in, const int* in_sizes, int n_in,
                              void* d_out, int out_size, void* d_ws, size_t ws_size,
                              hipStream_t stream)
{
    const float* x    = (const float*)d_in[0];
    const float* sW   = (const float*)d_in[1];
    const float* sb   = (const float*)d_in[2];
    const float* s_g  = (const float*)d_in[3];
    const float* s_b  = (const float*)d_in[4];
    const float* s_m  = (const float*)d_in[5];
    const float* s_v  = (const float*)d_in[6];
    const float* cW   = (const float*)d_in[7];
    const float* cb   = (const float*)d_in[8];
    const float* c_g  = (const float*)d_in[9];
    const float* c_b  = (const float*)d_in[10];
    const float* c_m  = (const float*)d_in[11];
    const float* c_v  = (const float*)d_in[12];
    const float* qW   = (const float*)d_in[13];
    const float* qb   = (const float*)d_in[14];
    const float* kW   = (const float*)d_in[15];
    const float* kb   = (const float*)d_in[16];
    const float* vW   = (const float*)d_in[17];
    const float* vb   = (const float*)d_in[18];
    const float* oW   = (const float*)d_in[19];
    const float* ob   = (const float*)d_in[20];
    const float* s_gamma = (const float*)d_in[21];
    const float* c_gamma = (const float*)d_in[22];

    float* ws    = (float*)d_ws;
    float* sx    = ws;                 // 524288 floats
    float* cx    = ws + 524288;        // 524288
    float* fused = ws + 1048576;       // 524288
    float* AcsT  = ws + 1572864;       // 8192
    float* Ac    = ws + 1581056;       // 8192
    unsigned short* us = (unsigned short*)(ws + 1589248);
    unsigned short* qT = us;           // 65536  ushort  [B][HW][8]
    unsigned short* kT = us + 65536;   // 65536  ushort  [B][HW][8]
    unsigned short* vS = us + 131072;  // 524288 ushort  [B][64][HW] (swizzled)

    hipMemsetAsync(Ac, 0, 2 * 64 * 64 * sizeof(float), stream);

    k_conv3<<<512, 256, 0, stream>>>(x, sW, sb, s_g, s_b, s_m, s_v,
                                     cW, cb, c_g, c_b, c_m, c_v, sx, cx);
    k_qkv<<<160, 256, 0, stream>>>(x, qW, qb, kW, kb, vW, vb, qT, kT, vS);
    k_gram<<<256, 256, 0, stream>>>(cx, Ac);
    k_csoft<<<128, 64, 0, stream>>>(Ac, AcsT);
    k_attn_mfma<<<256, 256, 0, stream>>>(qT, kT, vS, sx, s_gamma, fused);
    k_chapply<<<128, 256, 0, stream>>>(cx, AcsT, c_gamma, fused);
    k_outconv<<<128, 256, 0, stream>>>(fused, oW, ob, (float*)d_out);
}

// Round 3
// 235.585 us; speedup vs baseline: 1.7669x; 1.4718x over previous
//
#include <hip/hip_runtime.h>

#define HW 4096

typedef __attribute__((ext_vector_type(8)))  short short8;
typedef __attribute__((ext_vector_type(16))) float float16;

__device__ __forceinline__ unsigned short f2bf(float f) {
    unsigned u = __float_as_uint(f);
    u += 0x7fffu + ((u >> 16) & 1u);   // RNE
    return (unsigned short)(u >> 16);
}

// ---------------------------------------------------------------------------
// K0: weight prep. Wa[which][tap][oc][ic] bf16 (A-operand order) and fused
// BN scale/shift: scsh[which][0][oc]=scale, [1][oc]=(cb-m)*scale+beta.
// grid 18 = which(2) x tap(9), 256 thr.
// ---------------------------------------------------------------------------
__global__ __launch_bounds__(256) void k_wprep(
    const float* __restrict__ sW, const float* __restrict__ cW,
    const float* __restrict__ sb, const float* __restrict__ cb,
    const float* __restrict__ s_g, const float* __restrict__ s_b,
    const float* __restrict__ s_m, const float* __restrict__ s_v,
    const float* __restrict__ c_g, const float* __restrict__ c_b,
    const float* __restrict__ c_m, const float* __restrict__ c_v,
    unsigned short* __restrict__ Wa, float* __restrict__ scsh)
{
    int bx = blockIdx.x;
    int which = bx / 9, khw = bx % 9;
    const float* W = which ? cW : sW;
    int t = threadIdx.x;
#pragma unroll
    for (int i = 0; i < 16; i++) {
        int idx = t + 256 * i;            // 4096 = 64oc x 64ic
        int oc = idx >> 6, ic = idx & 63;
        float v = W[(size_t)(oc * 64 + ic) * 9 + khw];
        Wa[((size_t)(which * 9 + khw) * 64 + oc) * 64 + ic] = f2bf(v);
    }
    if (bx == 0 && t < 128) {
        int wh = t >> 6, oc = t & 63;
        const float* g  = wh ? c_g : s_g;
        const float* bb = wh ? c_b : s_b;
        const float* m  = wh ? c_m : s_m;
        const float* vv = wh ? c_v : s_v;
        const float* cbias = wh ? cb : sb;
        float scale = g[oc] * rsqrtf(vv[oc] + 1e-5f);
        scsh[wh * 128 + oc]      = scale;
        scsh[wh * 128 + 64 + oc] = (cbias[oc] - m[oc]) * scale + bb[oc];
    }
}

// ---------------------------------------------------------------------------
// K1: 3x3 conv + BN + ReLU via implicit-GEMM bf16 MFMA (32x32x16).
// K = tap(9) x ic(64) = 576. Block: 2 output rows x 64 cols x 64 oc.
// LDS x-tile: 4 rows (2 halo) x 66 cols (zero-padded) x 64 ic bf16,
// layout [lr][icg(8)][col(66)][8ic] -> B-frags are aligned b128 reads.
// Waves: w&1 -> row, w>>1 -> oc-half (m0). 72 MFMA/wave, 2 acc chains.
// grid 128 = which(2) x b(2) x rowpair(32).
// ---------------------------------------------------------------------------
__global__ __launch_bounds__(256) void k_conv3m(
    const float* __restrict__ x, const unsigned short* __restrict__ Wa,
    const float* __restrict__ scsh,
    float* __restrict__ sx, float* __restrict__ cx)
{
    __shared__ unsigned short xs[4 * 8 * 66 * 8];   // 33792 B

    int bx = blockIdx.x;
    int which = bx >> 6;
    int b     = (bx >> 5) & 1;
    int rp    = bx & 31;
    int r0 = rp * 2;
    int t = threadIdx.x;

    // ---- stage x-tile (rows r0-1 .. r0+2, bf16, zero-padded cols) ----
    const float* xb = x + (size_t)(b * 64) * HW;
#pragma unroll
    for (int it = 0; it < 32; it++) {
        int idx = t + 256 * it;            // 8192 uint writes
        int lr  = idx >> 11;
        int rem = idx & 2047;
        int icp = rem >> 6;                // ic pair 0..31
        int col = rem & 63;
        int ir  = r0 - 1 + lr;
        unsigned pack = 0;
        if (ir >= 0 && ir < 64) {
            float v0 = xb[(size_t)(icp * 2)     * HW + ir * 64 + col];
            float v1 = xb[(size_t)(icp * 2 + 1) * HW + ir * 64 + col];
            pack = (unsigned)f2bf(v0) | ((unsigned)f2bf(v1) << 16);
        }
        int icg = icp >> 2, io = icp & 3;
        *(unsigned*)&xs[(((lr * 8 + icg) * 66 + col + 1) * 8) + io * 2] = pack;
    }
    // zero edge columns (col 0 and 65): 4*8*2 groups x 4 uints = 256
    {
        int idx = t;                        // exactly 256 threads
        int pair = idx & 3;
        int colsel = (idx >> 2) & 1;
        int rg = idx >> 3;                  // lr*8+icg, 0..31
        *(unsigned*)&xs[((rg * 66 + colsel * 65) * 8) + pair * 2] = 0u;
    }
    __syncthreads();

    // ---- MFMA main loop ----
    int lane = t & 63, w = t >> 6;
    int l31 = lane & 31, half = lane >> 5;
    int row = r0 + (w & 1);
    int m0  = (w >> 1) * 32;

    float16 acc0, acc1;
#pragma unroll
    for (int i = 0; i < 16; i++) { acc0[i] = 0.f; acc1[i] = 0.f; }

    const unsigned short* Wbase =
        Wa + ((size_t)which * 9) * 4096 + (size_t)(m0 + l31) * 64 + half * 8;

#pragma unroll
    for (int khw = 0; khw < 9; khw++) {
        const int kh = khw / 3, kw = khw % 3;
        const int lrb = (w & 1) + kh;
#pragma unroll
        for (int icq = 0; icq < 4; icq++) {
            short8 af = *(const short8*)(Wbase + (size_t)khw * 4096 + icq * 16);
            const unsigned short* bp =
                &xs[((lrb * 8 + icq * 2 + half) * 66 + kw) * 8];
            short8 b0 = *(const short8*)(bp + (size_t)l31 * 8);
            short8 b1 = *(const short8*)(bp + (size_t)(l31 + 32) * 8);
            acc0 = __builtin_amdgcn_mfma_f32_32x32x16_bf16(af, b0, acc0, 0, 0, 0);
            acc1 = __builtin_amdgcn_mfma_f32_32x32x16_bf16(af, b1, acc1, 0, 0, 0);
        }
    }

    // ---- epilogue: BN + ReLU + store ----
    float* out = (which ? cx : sx) + (size_t)(b * 64) * HW;
    const float* sc = scsh + which * 128;
    int hwbase = row * 64 + l31;
#pragma unroll
    for (int r = 0; r < 16; r++) {
        int oc = m0 + (r & 3) + 8 * (r >> 2) + 4 * half;
        float s  = sc[oc];
        float sh = sc[64 + oc];
        float v0 = fmaxf(acc0[r] * s + sh, 0.f);
        float v1 = fmaxf(acc1[r] * s + sh, 0.f);
        out[(size_t)oc * HW + hwbase]      = v0;
        out[(size_t)oc * HW + hwbase + 32] = v1;
    }
}

// ---------------------------------------------------------------------------
// K2: 1x1 convs q,k,v -> bf16 MFMA-ready layouts (qT/kT [b][hw][8], vS
// swizzled [b][c][hw']). grid 160 = b(2) x chunk(16) x g(5).
// ---------------------------------------------------------------------------
__global__ __launch_bounds__(256) void k_qkv(
    const float* __restrict__ x,
    const float* __restrict__ qW, const float* __restrict__ qb,
    const float* __restrict__ kW, const float* __restrict__ kb,
    const float* __restrict__ vW, const float* __restrict__ vb,
    unsigned short* __restrict__ qT, unsigned short* __restrict__ kT,
    unsigned short* __restrict__ vS)
{
    int bx = blockIdx.x;
    int b = bx / 80, rem = bx % 80;
    int chunk = rem / 5, g = rem % 5;
    int t  = threadIdx.x;
    int hw = chunk * 256 + t;
    const float* xb = x + (size_t)(b * 64) * HW + hw;

    float acc[16];
#pragma unroll
    for (int u = 0; u < 16; u++) acc[u] = 0.f;

    if (g == 0) {
        for (int ic = 0; ic < 64; ic++) {
            float xv = xb[ic * HW];
#pragma unroll
            for (int u = 0; u < 8; u++) acc[u]     += qW[u * 64 + ic] * xv;
#pragma unroll
            for (int u = 0; u < 8; u++) acc[8 + u] += kW[u * 64 + ic] * xv;
        }
        short8 qv, kv;
#pragma unroll
        for (int u = 0; u < 8; u++) qv[u] = (short)f2bf(acc[u] + qb[u]);
#pragma unroll
        for (int u = 0; u < 8; u++) kv[u] = (short)f2bf(acc[8 + u] + kb[u]);
        *(short8*)(qT + ((size_t)(b * HW) + hw) * 8) = qv;
        *(short8*)(kT + ((size_t)(b * HW) + hw) * 8) = kv;
    } else {
        int c0 = (g - 1) * 16;
        for (int ic = 0; ic < 64; ic++) {
            float xv = xb[ic * HW];
#pragma unroll
            for (int u = 0; u < 16; u++) acc[u] += vW[(c0 + u) * 64 + ic] * xv;
        }
        int m  = hw & 15;
        int jp = (hw & ~15) | (m & 3) | ((m & 4) << 1) | ((m & 8) >> 1);
#pragma unroll
        for (int u = 0; u < 16; u++)
            vS[((size_t)(b * 64) + c0 + u) * HW + jp] = f2bf(acc[u] + vb[c0 + u]);
    }
}

// ---------------------------------------------------------------------------
// K3: spatial flash attention, bf16 MFMA (32x32x16), P stays in registers.
// grid 256 = b(2) x itile(128).
// ---------------------------------------------------------------------------
__global__ __launch_bounds__(256) void k_attn_mfma(
    const unsigned short* __restrict__ qT, const unsigned short* __restrict__ kT,
    const unsigned short* __restrict__ vS, const float* __restrict__ sx,
    const float* __restrict__ s_gamma, float* __restrict__ fused)
{
    __shared__ float o_sh[4][64][33];
    __shared__ float den_sh[4][32];

    int t = threadIdx.x;
    int lane = t & 63, w = t >> 6;
    int half = lane >> 5, l31 = lane & 31;
    int b  = blockIdx.x >> 7;
    int i0 = (blockIdx.x & 127) * 32;

    short8 qf;
    if (half == 0) {
        qf = *(const short8*)(qT + ((size_t)(b * HW) + i0 + l31) * 8);
    } else {
#pragma unroll
        for (int i = 0; i < 8; i++) qf[i] = 0;
    }

    float16 o0, o1;
#pragma unroll
    for (int i = 0; i < 16; i++) { o0[i] = 0.f; o1[i] = 0.f; }
    float denr = 0.f;

    const unsigned short* kTb = kT + (size_t)(b * HW) * 8;
    const unsigned short* vr0 = vS + ((size_t)(b * 64) + l31) * HW;
    const unsigned short* vr1 = vS + ((size_t)(b * 64) + 32 + l31) * HW;

    for (int tile = 0; tile < 32; tile++) {
        int j0 = w * 1024 + tile * 32;

        short8 kf;
        if (half == 0) {
            kf = *(const short8*)(kTb + (size_t)(j0 + l31) * 8);
        } else {
#pragma unroll
            for (int i = 0; i < 8; i++) kf[i] = 0;
        }

        float16 z;
#pragma unroll
        for (int i = 0; i < 16; i++) z[i] = 0.f;
        float16 s = __builtin_amdgcn_mfma_f32_32x32x16_bf16(kf, qf, z, 0, 0, 0);

        float p[16];
#pragma unroll
        for (int r = 0; r < 16; r++) {
            p[r] = __expf(s[r]);
            denr += p[r];
        }
        short8 pa0, pa1;
#pragma unroll
        for (int r = 0; r < 8; r++) {
            pa0[r] = (short)f2bf(p[r]);
            pa1[r] = (short)f2bf(p[8 + r]);
        }

        int off = j0 + half * 8;
        short8 v00 = *(const short8*)(vr0 + off);
        short8 v01 = *(const short8*)(vr1 + off);
        short8 v10 = *(const short8*)(vr0 + off + 16);
        short8 v11 = *(const short8*)(vr1 + off + 16);

        o0 = __builtin_amdgcn_mfma_f32_32x32x16_bf16(pa0, v00, o0, 0, 0, 0);
        o1 = __builtin_amdgcn_mfma_f32_32x32x16_bf16(pa0, v01, o1, 0, 0, 0);
        o0 = __builtin_amdgcn_mfma_f32_32x32x16_bf16(pa1, v10, o0, 0, 0, 0);
        o1 = __builtin_amdgcn_mfma_f32_32x32x16_bf16(pa1, v11, o1, 0, 0, 0);
    }

    float dfull = denr + __shfl_xor(denr, 32);
    if (half == 0) den_sh[w][l31] = dfull;
#pragma unroll
    for (int r = 0; r < 16; r++) {
        int il = (r & 3) + 8 * (r >> 2) + 4 * half;
        o_sh[w][l31][il]      = o0[r];
        o_sh[w][32 + l31][il] = o1[r];
    }
    __syncthreads();

    int i  = t & 31;
    int cg = t >> 5;
    float dtot = den_sh[0][i] + den_sh[1][i] + den_sh[2][i] + den_sh[3][i];
    float inv  = s_gamma[0] / dtot;
#pragma unroll
    for (int u = 0; u < 8; u++) {
        int c = cg * 8 + u;
        float sv = o_sh[0][c][i] + o_sh[1][c][i] + o_sh[2][c][i] + o_sh[3][c][i];
        size_t off = (size_t)(b * 64 + c) * HW + i0 + i;
        fused[off] = sv * inv + sx[off];
    }
}

// ---------------------------------------------------------------------------
// K4a: channel gram Ac[b,i,j] = sum_hw cx[i,hw]*cx[j,hw]
// ---------------------------------------------------------------------------
__global__ __launch_bounds__(256) void k_gram(
    const float* __restrict__ cx, float* __restrict__ Ac)
{
    int bx = blockIdx.x;
    int b = bx >> 7, rem = bx & 127;
    int ig = rem >> 3, sl = rem & 7;
    int i0 = ig * 4, hw0 = sl * 512;
    int t = threadIdx.x;
    int irow = t >> 6, l = t & 63;

    const float* cxb = cx + (size_t)(b * 64) * HW;
    const float* xip = cxb + (size_t)(i0 + irow) * HW + hw0 + l;

    float acc[64];
#pragma unroll
    for (int j = 0; j < 64; j++) acc[j] = 0.f;

    for (int it = 0; it < 8; it++) {
        int off = it * 64;
        float xv = xip[off];
        const float* base = cxb + hw0 + l + off;
#pragma unroll
        for (int j = 0; j < 64; j++)
            acc[j] += base[(size_t)j * HW] * xv;
    }

    float sel = 0.f;
#pragma unroll
    for (int j = 0; j < 64; j++) {
        float v = acc[j];
        v += __shfl_xor(v, 1);
        v += __shfl_xor(v, 2);
        v += __shfl_xor(v, 4);
        v += __shfl_xor(v, 8);
        v += __shfl_xor(v, 16);
        v += __shfl_xor(v, 32);
        sel = (l == j) ? v : sel;
    }
    atomicAdd(&Ac[(size_t)(b * 64 + i0 + irow) * 64 + l], sel);
}

// ---------------------------------------------------------------------------
// K4b: row softmax of (max - A) via min-trick; writes transposed AcsT[b][j][i]
// ---------------------------------------------------------------------------
__global__ __launch_bounds__(64) void k_csoft(
    const float* __restrict__ Ac, float* __restrict__ AcsT)
{
    int row = blockIdx.x;
    int b = row >> 6, i = row & 63;
    int j = threadIdx.x;
    float a = Ac[(size_t)(b * 64 + i) * 64 + j];
    float mn = a;
    mn = fminf(mn, __shfl_xor(mn, 1));
    mn = fminf(mn, __shfl_xor(mn, 2));
    mn = fminf(mn, __shfl_xor(mn, 4));
    mn = fminf(mn, __shfl_xor(mn, 8));
    mn = fminf(mn, __shfl_xor(mn, 16));
    mn = fminf(mn, __shfl_xor(mn, 32));
    float p = __expf(mn - a);
    float s = p;
    s += __shfl_xor(s, 1);
    s += __shfl_xor(s, 2);
    s += __shfl_xor(s, 4);
    s += __shfl_xor(s, 8);
    s += __shfl_xor(s, 16);
    s += __shfl_xor(s, 32);
    AcsT[(size_t)b * 4096 + j * 64 + i] = p / s;
}

// ---------------------------------------------------------------------------
// K5: ca = AcsT^T @ cx ; fused += c_gamma*ca + cx
// ---------------------------------------------------------------------------
__global__ __launch_bounds__(256) void k_chapply(
    const float* __restrict__ cx, const float* __restrict__ AcsT,
    const float* __restrict__ c_gamma, float* __restrict__ fused)
{
    __shared__ float asl[64][68];
    int bx = blockIdx.x;
    int b = bx >> 6, rem = bx & 63;
    int chunk = rem >> 2, cgp = rem & 3;
    int i0 = cgp * 16;
    int t = threadIdx.x;
    int hw = chunk * 256 + t;

#pragma unroll
    for (int rr = 0; rr < 16; rr++) {
        int idx = t + 256 * rr;
        int j = idx >> 6, i = idx & 63;
        asl[j][i] = AcsT[(size_t)b * 4096 + idx];
    }
    __syncthreads();

    const float* cxb = cx + (size_t)(b * 64) * HW + hw;
    float acc[16] = {};
    for (int j = 0; j < 64; j++) {
        float xv = cxb[(size_t)j * HW];
        float4 a0 = *(const float4*)&asl[j][i0];
        float4 a1 = *(const float4*)&asl[j][i0 + 4];
        float4 a2 = *(const float4*)&asl[j][i0 + 8];
        float4 a3 = *(const float4*)&asl[j][i0 + 12];
        acc[0]  += a0.x * xv; acc[1]  += a0.y * xv; acc[2]  += a0.z * xv; acc[3]  += a0.w * xv;
        acc[4]  += a1.x * xv; acc[5]  += a1.y * xv; acc[6]  += a1.z * xv; acc[7]  += a1.w * xv;
        acc[8]  += a2.x * xv; acc[9]  += a2.y * xv; acc[10] += a2.z * xv; acc[11] += a2.w * xv;
        acc[12] += a3.x * xv; acc[13] += a3.y * xv; acc[14] += a3.z * xv; acc[15] += a3.w * xv;
    }

    float cgam = c_gamma[0];
#pragma unroll
    for (int u = 0; u < 16; u++) {
        int i = i0 + u;
        size_t o = (size_t)(b * 64 + i) * HW + hw;
        fused[o] = fused[o] + cgam * acc[u] + cx[(size_t)(b * 64 + i) * HW + hw];
    }
}

// ---------------------------------------------------------------------------
// K6: out = oW @ fused + ob
// ---------------------------------------------------------------------------
__global__ __launch_bounds__(256) void k_outconv(
    const float* __restrict__ fused, const float* __restrict__ oW,
    const float* __restrict__ ob, float* __restrict__ out)
{
    int bx = blockIdx.x;
    int b = bx >> 6, rem = bx & 63;
    int chunk = rem >> 2, og = rem & 3;
    int o0 = og * 16;
    int t = threadIdx.x;
    int hw = chunk * 256 + t;

    const float* fb = fused + (size_t)(b * 64) * HW + hw;
    float acc[16] = {};
    for (int c = 0; c < 64; c++) {
        float fv = fb[(size_t)c * HW];
#pragma unroll
        for (int u = 0; u < 16; u++)
            acc[u] += oW[(o0 + u) * 64 + c] * fv;
    }
#pragma unroll
    for (int u = 0; u < 16; u++)
        out[(size_t)(b * 64 + o0 + u) * HW + hw] = acc[u] + ob[o0 + u];
}

// ---------------------------------------------------------------------------
extern "C" void kernel_launch(void* const* d_in, const int* in_sizes, int n_in,
                              void* d_out, int out_size, void* d_ws, size_t ws_size,
                              hipStream_t stream)
{
    const float* x    = (const float*)d_in[0];
    const float* sW   = (const float*)d_in[1];
    const float* sb   = (const float*)d_in[2];
    const float* s_g  = (const float*)d_in[3];
    const float* s_b  = (const float*)d_in[4];
    const float* s_m  = (const float*)d_in[5];
    const float* s_v  = (const float*)d_in[6];
    const float* cW   = (const float*)d_in[7];
    const float* cb   = (const float*)d_in[8];
    const float* c_g  = (const float*)d_in[9];
    const float* c_b  = (const float*)d_in[10];
    const float* c_m  = (const float*)d_in[11];
    const float* c_v  = (const float*)d_in[12];
    const float* qW   = (const float*)d_in[13];
    const float* qb   = (const float*)d_in[14];
    const float* kW   = (const float*)d_in[15];
    const float* kb   = (const float*)d_in[16];
    const float* vW   = (const float*)d_in[17];
    const float* vb   = (const float*)d_in[18];
    const float* oW   = (const float*)d_in[19];
    const float* ob   = (const float*)d_in[20];
    const float* s_gamma = (const float*)d_in[21];
    const float* c_gamma = (const float*)d_in[22];

    float* ws    = (float*)d_ws;
    float* sx    = ws;                 // 524288 floats
    float* cx    = ws + 524288;        // 524288
    float* fused = ws + 1048576;       // 524288
    float* AcsT  = ws + 1572864;       // 8192
    float* Ac    = ws + 1581056;       // 8192
    float* scsh  = ws + 1589248;       // 256 (2 which x {scale,shift} x 64)
    unsigned short* us = (unsigned short*)(ws + 1589504);
    unsigned short* qT = us;           // 65536  ushort  [B][HW][8]
    unsigned short* kT = us + 65536;   // 65536  ushort  [B][HW][8]
    unsigned short* vS = us + 131072;  // 524288 ushort  [B][64][HW] (swizzled)
    unsigned short* Wa = us + 655360;  // 73728  ushort  [2][9][64oc][64ic]

    hipMemsetAsync(Ac, 0, 2 * 64 * 64 * sizeof(float), stream);

    k_wprep<<<18, 256, 0, stream>>>(sW, cW, sb, cb, s_g, s_b, s_m, s_v,
                                    c_g, c_b, c_m, c_v, Wa, scsh);
    k_conv3m<<<128, 256, 0, stream>>>(x, Wa, scsh, sx, cx);
    k_qkv<<<160, 256, 0, stream>>>(x, qW, qb, kW, kb, vW, vb, qT, kT, vS);
    k_gram<<<256, 256, 0, stream>>>(cx, Ac);
    k_csoft<<<128, 64, 0, stream>>>(Ac, AcsT);
    k_attn_mfma<<<256, 256, 0, stream>>>(qT, kT, vS, sx, s_gamma, fused);
    k_chapply<<<128, 256, 0, stream>>>(cx, AcsT, c_gamma, fused);
    k_outconv<<<128, 256, 0, stream>>>(fused, oW, ob, (float*)d_out);
}

// Round 4
// 219.058 us; speedup vs baseline: 1.9002x; 1.0754x over previous
//
#include <hip/hip_runtime.h>

#define HW 4096

typedef __attribute__((ext_vector_type(8)))  short short8;
typedef __attribute__((ext_vector_type(16))) float float16;

__device__ __forceinline__ unsigned short f2bf(float f) {
    unsigned u = __float_as_uint(f);
    u += 0x7fffu + ((u >> 16) & 1u);   // RNE
    return (unsigned short)(u >> 16);
}

// ---------------------------------------------------------------------------
// K0: weight prep. Wa[which][tap][oc][ic] bf16 (A-operand order) and fused
// BN scale/shift: scsh[which][0][oc]=scale, [1][oc]=(cb-m)*scale+beta.
// ---------------------------------------------------------------------------
__global__ __launch_bounds__(256) void k_wprep(
    const float* __restrict__ sW, const float* __restrict__ cW,
    const float* __restrict__ sb, const float* __restrict__ cb,
    const float* __restrict__ s_g, const float* __restrict__ s_b,
    const float* __restrict__ s_m, const float* __restrict__ s_v,
    const float* __restrict__ c_g, const float* __restrict__ c_b,
    const float* __restrict__ c_m, const float* __restrict__ c_v,
    unsigned short* __restrict__ Wa, float* __restrict__ scsh)
{
    int bx = blockIdx.x;
    int which = bx / 9, khw = bx % 9;
    const float* W = which ? cW : sW;
    int t = threadIdx.x;
#pragma unroll
    for (int i = 0; i < 16; i++) {
        int idx = t + 256 * i;            // 4096 = 64oc x 64ic
        int oc = idx >> 6, ic = idx & 63;
        float v = W[(size_t)(oc * 64 + ic) * 9 + khw];
        Wa[((size_t)(which * 9 + khw) * 64 + oc) * 64 + ic] = f2bf(v);
    }
    if (bx == 0 && t < 128) {
        int wh = t >> 6, oc = t & 63;
        const float* g  = wh ? c_g : s_g;
        const float* bb = wh ? c_b : s_b;
        const float* m  = wh ? c_m : s_m;
        const float* vv = wh ? c_v : s_v;
        const float* cbias = wh ? cb : sb;
        float scale = g[oc] * rsqrtf(vv[oc] + 1e-5f);
        scsh[wh * 128 + oc]      = scale;
        scsh[wh * 128 + 64 + oc] = (cbias[oc] - m[oc]) * scale + bb[oc];
    }
}

// ---------------------------------------------------------------------------
// K1: 3x3 conv + BN + ReLU via implicit-GEMM bf16 MFMA (32x32x16).
// grid 128 = which(2) x b(2) x rowpair(32).
// ---------------------------------------------------------------------------
__global__ __launch_bounds__(256) void k_conv3m(
    const float* __restrict__ x, const unsigned short* __restrict__ Wa,
    const float* __restrict__ scsh,
    float* __restrict__ sx, float* __restrict__ cx)
{
    __shared__ unsigned short xs[4 * 8 * 66 * 8];   // 33792 B

    int bx = blockIdx.x;
    int which = bx >> 6;
    int b     = (bx >> 5) & 1;
    int rp    = bx & 31;
    int r0 = rp * 2;
    int t = threadIdx.x;

    const float* xb = x + (size_t)(b * 64) * HW;
#pragma unroll
    for (int it = 0; it < 32; it++) {
        int idx = t + 256 * it;            // 8192 uint writes
        int lr  = idx >> 11;
        int rem = idx & 2047;
        int icp = rem >> 6;
        int col = rem & 63;
        int ir  = r0 - 1 + lr;
        unsigned pack = 0;
        if (ir >= 0 && ir < 64) {
            float v0 = xb[(size_t)(icp * 2)     * HW + ir * 64 + col];
            float v1 = xb[(size_t)(icp * 2 + 1) * HW + ir * 64 + col];
            pack = (unsigned)f2bf(v0) | ((unsigned)f2bf(v1) << 16);
        }
        int icg = icp >> 2, io = icp & 3;
        *(unsigned*)&xs[(((lr * 8 + icg) * 66 + col + 1) * 8) + io * 2] = pack;
    }
    {
        int idx = t;
        int pair = idx & 3;
        int colsel = (idx >> 2) & 1;
        int rg = idx >> 3;
        *(unsigned*)&xs[((rg * 66 + colsel * 65) * 8) + pair * 2] = 0u;
    }
    __syncthreads();

    int lane = t & 63, w = t >> 6;
    int l31 = lane & 31, half = lane >> 5;
    int row = r0 + (w & 1);
    int m0  = (w >> 1) * 32;

    float16 acc0, acc1;
#pragma unroll
    for (int i = 0; i < 16; i++) { acc0[i] = 0.f; acc1[i] = 0.f; }

    const unsigned short* Wbase =
        Wa + ((size_t)which * 9) * 4096 + (size_t)(m0 + l31) * 64 + half * 8;

#pragma unroll
    for (int khw = 0; khw < 9; khw++) {
        const int kh = khw / 3, kw = khw % 3;
        const int lrb = (w & 1) + kh;
#pragma unroll
        for (int icq = 0; icq < 4; icq++) {
            short8 af = *(const short8*)(Wbase + (size_t)khw * 4096 + icq * 16);
            const unsigned short* bp =
                &xs[((lrb * 8 + icq * 2 + half) * 66 + kw) * 8];
            short8 b0 = *(const short8*)(bp + (size_t)l31 * 8);
            short8 b1 = *(const short8*)(bp + (size_t)(l31 + 32) * 8);
            acc0 = __builtin_amdgcn_mfma_f32_32x32x16_bf16(af, b0, acc0, 0, 0, 0);
            acc1 = __builtin_amdgcn_mfma_f32_32x32x16_bf16(af, b1, acc1, 0, 0, 0);
        }
    }

    float* out = (which ? cx : sx) + (size_t)(b * 64) * HW;
    const float* sc = scsh + which * 128;
    int hwbase = row * 64 + l31;
#pragma unroll
    for (int r = 0; r < 16; r++) {
        int oc = m0 + (r & 3) + 8 * (r >> 2) + 4 * half;
        float s  = sc[oc];
        float sh = sc[64 + oc];
        float v0 = fmaxf(acc0[r] * s + sh, 0.f);
        float v1 = fmaxf(acc1[r] * s + sh, 0.f);
        out[(size_t)oc * HW + hwbase]      = v0;
        out[(size_t)oc * HW + hwbase + 32] = v1;
    }
}

// ---------------------------------------------------------------------------
// K2: 1x1 convs q,k,v -> bf16 MFMA-ready layouts. grid 160.
// ---------------------------------------------------------------------------
__global__ __launch_bounds__(256) void k_qkv(
    const float* __restrict__ x,
    const float* __restrict__ qW, const float* __restrict__ qb,
    const float* __restrict__ kW, const float* __restrict__ kb,
    const float* __restrict__ vW, const float* __restrict__ vb,
    unsigned short* __restrict__ qT, unsigned short* __restrict__ kT,
    unsigned short* __restrict__ vS)
{
    int bx = blockIdx.x;
    int b = bx / 80, rem = bx % 80;
    int chunk = rem / 5, g = rem % 5;
    int t  = threadIdx.x;
    int hw = chunk * 256 + t;
    const float* xb = x + (size_t)(b * 64) * HW + hw;

    float acc[16];
#pragma unroll
    for (int u = 0; u < 16; u++) acc[u] = 0.f;

    if (g == 0) {
        for (int ic = 0; ic < 64; ic++) {
            float xv = xb[ic * HW];
#pragma unroll
            for (int u = 0; u < 8; u++) acc[u]     += qW[u * 64 + ic] * xv;
#pragma unroll
            for (int u = 0; u < 8; u++) acc[8 + u] += kW[u * 64 + ic] * xv;
        }
        short8 qv, kv;
#pragma unroll
        for (int u = 0; u < 8; u++) qv[u] = (short)f2bf(acc[u] + qb[u]);
#pragma unroll
        for (int u = 0; u < 8; u++) kv[u] = (short)f2bf(acc[8 + u] + kb[u]);
        *(short8*)(qT + ((size_t)(b * HW) + hw) * 8) = qv;
        *(short8*)(kT + ((size_t)(b * HW) + hw) * 8) = kv;
    } else {
        int c0 = (g - 1) * 16;
        for (int ic = 0; ic < 64; ic++) {
            float xv = xb[ic * HW];
#pragma unroll
            for (int u = 0; u < 16; u++) acc[u] += vW[(c0 + u) * 64 + ic] * xv;
        }
        int m  = hw & 15;
        int jp = (hw & ~15) | (m & 3) | ((m & 4) << 1) | ((m & 8) >> 1);
#pragma unroll
        for (int u = 0; u < 16; u++)
            vS[((size_t)(b * 64) + c0 + u) * HW + jp] = f2bf(acc[u] + vb[c0 + u]);
    }
}

// ---------------------------------------------------------------------------
// K3: spatial flash attention, bf16 MFMA (32x32x16), P stays in registers.
// grid 256 = b(2) x itile(128).
// ---------------------------------------------------------------------------
__global__ __launch_bounds__(256) void k_attn_mfma(
    const unsigned short* __restrict__ qT, const unsigned short* __restrict__ kT,
    const unsigned short* __restrict__ vS, const float* __restrict__ sx,
    const float* __restrict__ s_gamma, float* __restrict__ fused)
{
    __shared__ float o_sh[4][64][33];
    __shared__ float den_sh[4][32];

    int t = threadIdx.x;
    int lane = t & 63, w = t >> 6;
    int half = lane >> 5, l31 = lane & 31;
    int b  = blockIdx.x >> 7;
    int i0 = (blockIdx.x & 127) * 32;

    short8 qf;
    if (half == 0) {
        qf = *(const short8*)(qT + ((size_t)(b * HW) + i0 + l31) * 8);
    } else {
#pragma unroll
        for (int i = 0; i < 8; i++) qf[i] = 0;
    }

    float16 o0, o1;
#pragma unroll
    for (int i = 0; i < 16; i++) { o0[i] = 0.f; o1[i] = 0.f; }
    float denr = 0.f;

    const unsigned short* kTb = kT + (size_t)(b * HW) * 8;
    const unsigned short* vr0 = vS + ((size_t)(b * 64) + l31) * HW;
    const unsigned short* vr1 = vS + ((size_t)(b * 64) + 32 + l31) * HW;

    for (int tile = 0; tile < 32; tile++) {
        int j0 = w * 1024 + tile * 32;

        short8 kf;
        if (half == 0) {
            kf = *(const short8*)(kTb + (size_t)(j0 + l31) * 8);
        } else {
#pragma unroll
            for (int i = 0; i < 8; i++) kf[i] = 0;
        }

        float16 z;
#pragma unroll
        for (int i = 0; i < 16; i++) z[i] = 0.f;
        float16 s = __builtin_amdgcn_mfma_f32_32x32x16_bf16(kf, qf, z, 0, 0, 0);

        float p[16];
#pragma unroll
        for (int r = 0; r < 16; r++) {
            p[r] = __expf(s[r]);
            denr += p[r];
        }
        short8 pa0, pa1;
#pragma unroll
        for (int r = 0; r < 8; r++) {
            pa0[r] = (short)f2bf(p[r]);
            pa1[r] = (short)f2bf(p[8 + r]);
        }

        int off = j0 + half * 8;
        short8 v00 = *(const short8*)(vr0 + off);
        short8 v01 = *(const short8*)(vr1 + off);
        short8 v10 = *(const short8*)(vr0 + off + 16);
        short8 v11 = *(const short8*)(vr1 + off + 16);

        o0 = __builtin_amdgcn_mfma_f32_32x32x16_bf16(pa0, v00, o0, 0, 0, 0);
        o1 = __builtin_amdgcn_mfma_f32_32x32x16_bf16(pa0, v01, o1, 0, 0, 0);
        o0 = __builtin_amdgcn_mfma_f32_32x32x16_bf16(pa1, v10, o0, 0, 0, 0);
        o1 = __builtin_amdgcn_mfma_f32_32x32x16_bf16(pa1, v11, o1, 0, 0, 0);
    }

    float dfull = denr + __shfl_xor(denr, 32);
    if (half == 0) den_sh[w][l31] = dfull;
#pragma unroll
    for (int r = 0; r < 16; r++) {
        int il = (r & 3) + 8 * (r >> 2) + 4 * half;
        o_sh[w][l31][il]      = o0[r];
        o_sh[w][32 + l31][il] = o1[r];
    }
    __syncthreads();

    int i  = t & 31;
    int cg = t >> 5;
    float dtot = den_sh[0][i] + den_sh[1][i] + den_sh[2][i] + den_sh[3][i];
    float inv  = s_gamma[0] / dtot;
#pragma unroll
    for (int u = 0; u < 8; u++) {
        int c = cg * 8 + u;
        float sv = o_sh[0][c][i] + o_sh[1][c][i] + o_sh[2][c][i] + o_sh[3][c][i];
        size_t off = (size_t)(b * 64 + c) * HW + i0 + i;
        fused[off] = sv * inv + sx[off];
    }
}

// ---------------------------------------------------------------------------
// K4a: channel gram via LDS-tiled outer product (fp32, no spills).
// grid 256 = b(2) x slice(128, 32 hw each). slab[hw][ch] transposed tile;
// 16x16 threads each own a 4x4 tile of the 64x64 gram; atomicAdd to Ac.
// ---------------------------------------------------------------------------
__global__ __launch_bounds__(256) void k_gram2(
    const float* __restrict__ cx, float* __restrict__ Ac)
{
    __shared__ float slab[32][68];

    int bx = blockIdx.x;
    int b = bx >> 7, slice = bx & 127;
    int hw0 = slice * 32;
    int t = threadIdx.x;

    // stage slab[hw][ch]: per idx -> one b128 LDS write of 4 consecutive ch
#pragma unroll
    for (int it = 0; it < 2; it++) {
        int idx = t + 256 * it;          // 512 = hw(32) x cgroup(16)
        int hw = idx & 31, c0 = (idx >> 5) * 4;
        float4 vv;
        vv.x = cx[(size_t)(b * 64 + c0 + 0) * HW + hw0 + hw];
        vv.y = cx[(size_t)(b * 64 + c0 + 1) * HW + hw0 + hw];
        vv.z = cx[(size_t)(b * 64 + c0 + 2) * HW + hw0 + hw];
        vv.w = cx[(size_t)(b * 64 + c0 + 3) * HW + hw0 + hw];
        *(float4*)&slab[hw][c0] = vv;
    }
    __syncthreads();

    int i0 = (t & 15) * 4, j0 = (t >> 4) * 4;
    float acc[4][4] = {};
#pragma unroll 8
    for (int hw = 0; hw < 32; hw++) {
        float4 ai = *(const float4*)&slab[hw][i0];
        float4 aj = *(const float4*)&slab[hw][j0];   // broadcast within phase
        acc[0][0] += ai.x * aj.x; acc[0][1] += ai.x * aj.y;
        acc[0][2] += ai.x * aj.z; acc[0][3] += ai.x * aj.w;
        acc[1][0] += ai.y * aj.x; acc[1][1] += ai.y * aj.y;
        acc[1][2] += ai.y * aj.z; acc[1][3] += ai.y * aj.w;
        acc[2][0] += ai.z * aj.x; acc[2][1] += ai.z * aj.y;
        acc[2][2] += ai.z * aj.z; acc[2][3] += ai.z * aj.w;
        acc[3][0] += ai.w * aj.x; acc[3][1] += ai.w * aj.y;
        acc[3][2] += ai.w * aj.z; acc[3][3] += ai.w * aj.w;
    }

    float* Ab = Ac + (size_t)(b * 64) * 64;
#pragma unroll
    for (int ii = 0; ii < 4; ii++)
#pragma unroll
        for (int jj = 0; jj < 4; jj++)
            atomicAdd(&Ab[(size_t)(i0 + ii) * 64 + j0 + jj], acc[ii][jj]);
}

// ---------------------------------------------------------------------------
// K4b: row softmax of (max - A) via min-trick; writes transposed AcsT[b][j][i]
// ---------------------------------------------------------------------------
__global__ __launch_bounds__(64) void k_csoft(
    const float* __restrict__ Ac, float* __restrict__ AcsT)
{
    int row = blockIdx.x;
    int b = row >> 6, i = row & 63;
    int j = threadIdx.x;
    float a = Ac[(size_t)(b * 64 + i) * 64 + j];
    float mn = a;
    mn = fminf(mn, __shfl_xor(mn, 1));
    mn = fminf(mn, __shfl_xor(mn, 2));
    mn = fminf(mn, __shfl_xor(mn, 4));
    mn = fminf(mn, __shfl_xor(mn, 8));
    mn = fminf(mn, __shfl_xor(mn, 16));
    mn = fminf(mn, __shfl_xor(mn, 32));
    float p = __expf(mn - a);
    float s = p;
    s += __shfl_xor(s, 1);
    s += __shfl_xor(s, 2);
    s += __shfl_xor(s, 4);
    s += __shfl_xor(s, 8);
    s += __shfl_xor(s, 16);
    s += __shfl_xor(s, 32);
    AcsT[(size_t)b * 4096 + j * 64 + i] = p / s;
}

// ---------------------------------------------------------------------------
// K5: ca = AcsT^T @ cx ; fused += c_gamma*ca + cx
// ---------------------------------------------------------------------------
__global__ __launch_bounds__(256) void k_chapply(
    const float* __restrict__ cx, const float* __restrict__ AcsT,
    const float* __restrict__ c_gamma, float* __restrict__ fused)
{
    __shared__ float asl[64][68];
    int bx = blockIdx.x;
    int b = bx >> 6, rem = bx & 63;
    int chunk = rem >> 2, cgp = rem & 3;
    int i0 = cgp * 16;
    int t = threadIdx.x;
    int hw = chunk * 256 + t;

#pragma unroll
    for (int rr = 0; rr < 16; rr++) {
        int idx = t + 256 * rr;
        int j = idx >> 6, i = idx & 63;
        asl[j][i] = AcsT[(size_t)b * 4096 + idx];
    }
    __syncthreads();

    const float* cxb = cx + (size_t)(b * 64) * HW + hw;
    float acc[16] = {};
    for (int j = 0; j < 64; j++) {
        float xv = cxb[(size_t)j * HW];
        float4 a0 = *(const float4*)&asl[j][i0];
        float4 a1 = *(const float4*)&asl[j][i0 + 4];
        float4 a2 = *(const float4*)&asl[j][i0 + 8];
        float4 a3 = *(const float4*)&asl[j][i0 + 12];
        acc[0]  += a0.x * xv; acc[1]  += a0.y * xv; acc[2]  += a0.z * xv; acc[3]  += a0.w * xv;
        acc[4]  += a1.x * xv; acc[5]  += a1.y * xv; acc[6]  += a1.z * xv; acc[7]  += a1.w * xv;
        acc[8]  += a2.x * xv; acc[9]  += a2.y * xv; acc[10] += a2.z * xv; acc[11] += a2.w * xv;
        acc[12] += a3.x * xv; acc[13] += a3.y * xv; acc[14] += a3.z * xv; acc[15] += a3.w * xv;
    }

    float cgam = c_gamma[0];
#pragma unroll
    for (int u = 0; u < 16; u++) {
        int i = i0 + u;
        size_t o = (size_t)(b * 64 + i) * HW + hw;
        fused[o] = fused[o] + cgam * acc[u] + cx[(size_t)(b * 64 + i) * HW + hw];
    }
}

// ---------------------------------------------------------------------------
// K6: out = oW @ fused + ob
// ---------------------------------------------------------------------------
__global__ __launch_bounds__(256) void k_outconv(
    const float* __restrict__ fused, const float* __restrict__ oW,
    const float* __restrict__ ob, float* __restrict__ out)
{
    int bx = blockIdx.x;
    int b = bx >> 6, rem = bx & 63;
    int chunk = rem >> 2, og = rem & 3;
    int o0 = og * 16;
    int t = threadIdx.x;
    int hw = chunk * 256 + t;

    const float* fb = fused + (size_t)(b * 64) * HW + hw;
    float acc[16] = {};
    for (int c = 0; c < 64; c++) {
        float fv = fb[(size_t)c * HW];
#pragma unroll
        for (int u = 0; u < 16; u++)
            acc[u] += oW[(o0 + u) * 64 + c] * fv;
    }
#pragma unroll
    for (int u = 0; u < 16; u++)
        out[(size_t)(b * 64 + o0 + u) * HW + hw] = acc[u] + ob[o0 + u];
}

// ---------------------------------------------------------------------------
extern "C" void kernel_launch(void* const* d_in, const int* in_sizes, int n_in,
                              void* d_out, int out_size, void* d_ws, size_t ws_size,
                              hipStream_t stream)
{
    const float* x    = (const float*)d_in[0];
    const float* sW   = (const float*)d_in[1];
    const float* sb   = (const float*)d_in[2];
    const float* s_g  = (const float*)d_in[3];
    const float* s_b  = (const float*)d_in[4];
    const float* s_m  = (const float*)d_in[5];
    const float* s_v  = (const float*)d_in[6];
    const float* cW   = (const float*)d_in[7];
    const float* cb   = (const float*)d_in[8];
    const float* c_g  = (const float*)d_in[9];
    const float* c_b  = (const float*)d_in[10];
    const float* c_m  = (const float*)d_in[11];
    const float* c_v  = (const float*)d_in[12];
    const float* qW   = (const float*)d_in[13];
    const float* qb   = (const float*)d_in[14];
    const float* kW   = (const float*)d_in[15];
    const float* kb   = (const float*)d_in[16];
    const float* vW   = (const float*)d_in[17];
    const float* vb   = (const float*)d_in[18];
    const float* oW   = (const float*)d_in[19];
    const float* ob   = (const float*)d_in[20];
    const float* s_gamma = (const float*)d_in[21];
    const float* c_gamma = (const float*)d_in[22];

    float* ws    = (float*)d_ws;
    float* sx    = ws;                 // 524288 floats
    float* cx    = ws + 524288;        // 524288
    float* fused = ws + 1048576;       // 524288
    float* AcsT  = ws + 1572864;       // 8192
    float* Ac    = ws + 1581056;       // 8192
    float* scsh  = ws + 1589248;       // 256
    unsigned short* us = (unsigned short*)(ws + 1589504);
    unsigned short* qT = us;           // 65536  ushort  [B][HW][8]
    unsigned short* kT = us + 65536;   // 65536  ushort  [B][HW][8]
    unsigned short* vS = us + 131072;  // 524288 ushort  [B][64][HW] (swizzled)
    unsigned short* Wa = us + 655360;  // 73728  ushort  [2][9][64oc][64ic]

    hipMemsetAsync(Ac, 0, 2 * 64 * 64 * sizeof(float), stream);

    k_wprep<<<18, 256, 0, stream>>>(sW, cW, sb, cb, s_g, s_b, s_m, s_v,
                                    c_g, c_b, c_m, c_v, Wa, scsh);
    k_conv3m<<<128, 256, 0, stream>>>(x, Wa, scsh, sx, cx);
    k_qkv<<<160, 256, 0, stream>>>(x, qW, qb, kW, kb, vW, vb, qT, kT, vS);
    k_gram2<<<256, 256, 0, stream>>>(cx, Ac);
    k_csoft<<<128, 64, 0, stream>>>(Ac, AcsT);
    k_attn_mfma<<<256, 256, 0, stream>>>(qT, kT, vS, sx, s_gamma, fused);
    k_chapply<<<128, 256, 0, stream>>>(cx, AcsT, c_gamma, fused);
    k_outconv<<<128, 256, 0, stream>>>(fused, oW, ob, (float*)d_out);
}

// Round 5
// 192.956 us; speedup vs baseline: 2.1573x; 1.1353x over previous
//
#include <hip/hip_runtime.h>

#define HW 4096

typedef __attribute__((ext_vector_type(8)))  short short8;
typedef __attribute__((ext_vector_type(16))) float float16;

__device__ __forceinline__ unsigned short f2bf(float f) {
    unsigned u = __float_as_uint(f);
    u += 0x7fffu + ((u >> 16) & 1u);   // RNE
    return (unsigned short)(u >> 16);
}

// ---------------------------------------------------------------------------
// K0: weight prep. Wa[which][tap][oc][ic] bf16 + fused BN scale/shift.
// ---------------------------------------------------------------------------
__global__ __launch_bounds__(256) void k_wprep(
    const float* __restrict__ sW, const float* __restrict__ cW,
    const float* __restrict__ sb, const float* __restrict__ cb,
    const float* __restrict__ s_g, const float* __restrict__ s_b,
    const float* __restrict__ s_m, const float* __restrict__ s_v,
    const float* __restrict__ c_g, const float* __restrict__ c_b,
    const float* __restrict__ c_m, const float* __restrict__ c_v,
    unsigned short* __restrict__ Wa, float* __restrict__ scsh)
{
    int bx = blockIdx.x;
    int which = bx / 9, khw = bx % 9;
    const float* W = which ? cW : sW;
    int t = threadIdx.x;
#pragma unroll
    for (int i = 0; i < 16; i++) {
        int idx = t + 256 * i;            // 4096 = 64oc x 64ic
        int oc = idx >> 6, ic = idx & 63;
        float v = W[(size_t)(oc * 64 + ic) * 9 + khw];
        Wa[((size_t)(which * 9 + khw) * 64 + oc) * 64 + ic] = f2bf(v);
    }
    if (bx == 0 && t < 128) {
        int wh = t >> 6, oc = t & 63;
        const float* g  = wh ? c_g : s_g;
        const float* bb = wh ? c_b : s_b;
        const float* m  = wh ? c_m : s_m;
        const float* vv = wh ? c_v : s_v;
        const float* cbias = wh ? cb : sb;
        float scale = g[oc] * rsqrtf(vv[oc] + 1e-5f);
        scsh[wh * 128 + oc]      = scale;
        scsh[wh * 128 + 64 + oc] = (cbias[oc] - m[oc]) * scale + bb[oc];
    }
}

// ---------------------------------------------------------------------------
// K1: 3x3 conv + BN + ReLU, implicit-GEMM bf16 MFMA. One output row / block.
// grid 256 = which(2) x b(2) x row(64). Waves: (col-half, oc-half).
// LDS: 3 halo rows x 8 icg x 66 cols x 8 ic bf16 = 25344 B.
// ---------------------------------------------------------------------------
__global__ __launch_bounds__(256) void k_conv3m(
    const float* __restrict__ x, const unsigned short* __restrict__ Wa,
    const float* __restrict__ scsh,
    float* __restrict__ sx, float* __restrict__ cx)
{
    __shared__ unsigned short xs[3 * 8 * 66 * 8];

    int bx = blockIdx.x;
    int which = bx >> 7;
    int b     = (bx >> 6) & 1;
    int row   = bx & 63;
    int t = threadIdx.x;

    const float* xb = x + (size_t)(b * 64) * HW;
#pragma unroll
    for (int it = 0; it < 24; it++) {
        int idx = t + 256 * it;            // 6144 uint packs
        int lr  = idx >> 11;               // 0..2
        int rem = idx & 2047;
        int icp = rem >> 6;
        int col = rem & 63;
        int ir  = row - 1 + lr;
        unsigned pack = 0;
        if (ir >= 0 && ir < 64) {
            float v0 = xb[(size_t)(icp * 2)     * HW + ir * 64 + col];
            float v1 = xb[(size_t)(icp * 2 + 1) * HW + ir * 64 + col];
            pack = (unsigned)f2bf(v0) | ((unsigned)f2bf(v1) << 16);
        }
        int icg = icp >> 2, io = icp & 3;
        *(unsigned*)&xs[(((lr * 8 + icg) * 66 + col + 1) * 8) + io * 2] = pack;
    }
    if (t < 192) {                          // zero cols 0 and 65
        int pair = t & 3;
        int colsel = (t >> 2) & 1;
        int rg = t >> 3;                    // 0..23
        *(unsigned*)&xs[((rg * 66 + colsel * 65) * 8) + pair * 2] = 0u;
    }
    __syncthreads();

    int lane = t & 63, w = t >> 6;
    int l31 = lane & 31, half = lane >> 5;
    int colh = w & 1;
    int m0   = (w >> 1) * 32;
    int c    = colh * 32 + l31;

    float16 acc;
#pragma unroll
    for (int i = 0; i < 16; i++) acc[i] = 0.f;

    const unsigned short* Wbase =
        Wa + ((size_t)which * 9) * 4096 + (size_t)(m0 + l31) * 64 + half * 8;

#pragma unroll
    for (int khw = 0; khw < 9; khw++) {
        const int kh = khw / 3, kw = khw % 3;
#pragma unroll
        for (int icq = 0; icq < 4; icq++) {
            short8 af = *(const short8*)(Wbase + (size_t)khw * 4096 + icq * 16);
            const unsigned short* bp =
                &xs[((kh * 8 + icq * 2 + half) * 66 + kw) * 8];
            short8 bf = *(const short8*)(bp + (size_t)c * 8);
            acc = __builtin_amdgcn_mfma_f32_32x32x16_bf16(af, bf, acc, 0, 0, 0);
        }
    }

    float* out = (which ? cx : sx) + (size_t)(b * 64) * HW;
    const float* sc = scsh + which * 128;
    int hwbase = row * 64 + c;
#pragma unroll
    for (int r = 0; r < 16; r++) {
        int oc = m0 + (r & 3) + 8 * (r >> 2) + 4 * half;
        float s  = sc[oc];
        float sh = sc[64 + oc];
        out[(size_t)oc * HW + hwbase] = fmaxf(acc[r] * s + sh, 0.f);
    }
}

// ---------------------------------------------------------------------------
// K2: 1x1 convs q,k,v -> bf16 MFMA-ready layouts.
// grid 640 = b(2) x chunk(64: 64px) x g(5), 64 threads (1 wave).
// ---------------------------------------------------------------------------
__global__ __launch_bounds__(64) void k_qkv(
    const float* __restrict__ x,
    const float* __restrict__ qW, const float* __restrict__ qb,
    const float* __restrict__ kW, const float* __restrict__ kb,
    const float* __restrict__ vW, const float* __restrict__ vb,
    unsigned short* __restrict__ qT, unsigned short* __restrict__ kT,
    unsigned short* __restrict__ vS)
{
    int bx = blockIdx.x;
    int b = bx / 320, rem = bx % 320;
    int chunk = rem / 5, g = rem % 5;
    int t  = threadIdx.x;
    int hw = chunk * 64 + t;
    const float* xb = x + (size_t)(b * 64) * HW + hw;

    float acc[16];
#pragma unroll
    for (int u = 0; u < 16; u++) acc[u] = 0.f;

    if (g == 0) {
        for (int ic = 0; ic < 64; ic++) {
            float xv = xb[ic * HW];
#pragma unroll
            for (int u = 0; u < 8; u++) acc[u]     += qW[u * 64 + ic] * xv;
#pragma unroll
            for (int u = 0; u < 8; u++) acc[8 + u] += kW[u * 64 + ic] * xv;
        }
        short8 qv, kv;
#pragma unroll
        for (int u = 0; u < 8; u++) qv[u] = (short)f2bf(acc[u] + qb[u]);
#pragma unroll
        for (int u = 0; u < 8; u++) kv[u] = (short)f2bf(acc[8 + u] + kb[u]);
        *(short8*)(qT + ((size_t)(b * HW) + hw) * 8) = qv;
        *(short8*)(kT + ((size_t)(b * HW) + hw) * 8) = kv;
    } else {
        int c0 = (g - 1) * 16;
        for (int ic = 0; ic < 64; ic++) {
            float xv = xb[ic * HW];
#pragma unroll
            for (int u = 0; u < 16; u++) acc[u] += vW[(c0 + u) * 64 + ic] * xv;
        }
        int m  = hw & 15;
        int jp = (hw & ~15) | (m & 3) | ((m & 4) << 1) | ((m & 8) >> 1);
#pragma unroll
        for (int u = 0; u < 16; u++)
            vS[((size_t)(b * 64) + c0 + u) * HW + jp] = f2bf(acc[u] + vb[c0 + u]);
    }
}

// ---------------------------------------------------------------------------
// K3: spatial flash attention, bf16 MFMA, j-split x2 -> unnormalized partials.
// grid 512 = b(2) x itile(128) x jh(2). Each wave: 16 j-tiles of 32.
// Opart[(jh*2+b)*64+c][HW], denp[jh*8192 + b*4096 + i].
// ---------------------------------------------------------------------------
__global__ __launch_bounds__(256) void k_attn_mfma(
    const unsigned short* __restrict__ qT, const unsigned short* __restrict__ kT,
    const unsigned short* __restrict__ vS,
    float* __restrict__ Opart, float* __restrict__ denp)
{
    __shared__ float o_sh[4][64][33];
    __shared__ float den_sh[4][32];

    int t = threadIdx.x;
    int lane = t & 63, w = t >> 6;
    int half = lane >> 5, l31 = lane & 31;
    int bx = blockIdx.x;
    int b  = bx >> 8;
    int itile = (bx >> 1) & 127;
    int jh = bx & 1;
    int i0 = itile * 32;

    short8 qf;
    if (half == 0) {
        qf = *(const short8*)(qT + ((size_t)(b * HW) + i0 + l31) * 8);
    } else {
#pragma unroll
        for (int i = 0; i < 8; i++) qf[i] = 0;
    }

    float16 o0, o1;
#pragma unroll
    for (int i = 0; i < 16; i++) { o0[i] = 0.f; o1[i] = 0.f; }
    float denr = 0.f;

    const unsigned short* kTb = kT + (size_t)(b * HW) * 8;
    const unsigned short* vr0 = vS + ((size_t)(b * 64) + l31) * HW;
    const unsigned short* vr1 = vS + ((size_t)(b * 64) + 32 + l31) * HW;

    for (int tile = 0; tile < 16; tile++) {
        int j0 = jh * 2048 + w * 512 + tile * 32;

        short8 kf;
        if (half == 0) {
            kf = *(const short8*)(kTb + (size_t)(j0 + l31) * 8);
        } else {
#pragma unroll
            for (int i = 0; i < 8; i++) kf[i] = 0;
        }

        float16 z;
#pragma unroll
        for (int i = 0; i < 16; i++) z[i] = 0.f;
        float16 s = __builtin_amdgcn_mfma_f32_32x32x16_bf16(kf, qf, z, 0, 0, 0);

        float p[16];
#pragma unroll
        for (int r = 0; r < 16; r++) {
            p[r] = __expf(s[r]);
            denr += p[r];
        }
        short8 pa0, pa1;
#pragma unroll
        for (int r = 0; r < 8; r++) {
            pa0[r] = (short)f2bf(p[r]);
            pa1[r] = (short)f2bf(p[8 + r]);
        }

        int off = j0 + half * 8;
        short8 v00 = *(const short8*)(vr0 + off);
        short8 v01 = *(const short8*)(vr1 + off);
        short8 v10 = *(const short8*)(vr0 + off + 16);
        short8 v11 = *(const short8*)(vr1 + off + 16);

        o0 = __builtin_amdgcn_mfma_f32_32x32x16_bf16(pa0, v00, o0, 0, 0, 0);
        o1 = __builtin_amdgcn_mfma_f32_32x32x16_bf16(pa0, v01, o1, 0, 0, 0);
        o0 = __builtin_amdgcn_mfma_f32_32x32x16_bf16(pa1, v10, o0, 0, 0, 0);
        o1 = __builtin_amdgcn_mfma_f32_32x32x16_bf16(pa1, v11, o1, 0, 0, 0);
    }

    float dfull = denr + __shfl_xor(denr, 32);
    if (half == 0) den_sh[w][l31] = dfull;
#pragma unroll
    for (int r = 0; r < 16; r++) {
        int il = (r & 3) + 8 * (r >> 2) + 4 * half;
        o_sh[w][l31][il]      = o0[r];
        o_sh[w][32 + l31][il] = o1[r];
    }
    __syncthreads();

    int i  = t & 31;
    int cg = t >> 5;
    if (cg == 0)
        denp[jh * 8192 + b * 4096 + i0 + i] =
            den_sh[0][i] + den_sh[1][i] + den_sh[2][i] + den_sh[3][i];
#pragma unroll
    for (int u = 0; u < 8; u++) {
        int c = cg * 8 + u;
        float sv = o_sh[0][c][i] + o_sh[1][c][i] + o_sh[2][c][i] + o_sh[3][c][i];
        Opart[((size_t)(jh * 2 + b) * 64 + c) * HW + i0 + i] = sv;
    }
}

// ---------------------------------------------------------------------------
// K4a: channel gram partials (no atomics): Gpart[b][slice][64][64].
// grid 256 = b(2) x slice(128, 32 hw each).
// ---------------------------------------------------------------------------
__global__ __launch_bounds__(256) void k_gram2(
    const float* __restrict__ cx, float* __restrict__ Gpart)
{
    __shared__ float slab[32][68];

    int bx = blockIdx.x;
    int b = bx >> 7, slice = bx & 127;
    int hw0 = slice * 32;
    int t = threadIdx.x;

#pragma unroll
    for (int it = 0; it < 2; it++) {
        int idx = t + 256 * it;          // 512 = hw(32) x cgroup(16)
        int hw = idx & 31, c0 = (idx >> 5) * 4;
        float4 vv;
        vv.x = cx[(size_t)(b * 64 + c0 + 0) * HW + hw0 + hw];
        vv.y = cx[(size_t)(b * 64 + c0 + 1) * HW + hw0 + hw];
        vv.z = cx[(size_t)(b * 64 + c0 + 2) * HW + hw0 + hw];
        vv.w = cx[(size_t)(b * 64 + c0 + 3) * HW + hw0 + hw];
        *(float4*)&slab[hw][c0] = vv;
    }
    __syncthreads();

    int i0 = (t & 15) * 4, j0 = (t >> 4) * 4;
    float acc[4][4] = {};
#pragma unroll 8
    for (int hw = 0; hw < 32; hw++) {
        float4 ai = *(const float4*)&slab[hw][i0];
        float4 aj = *(const float4*)&slab[hw][j0];
        acc[0][0] += ai.x * aj.x; acc[0][1] += ai.x * aj.y;
        acc[0][2] += ai.x * aj.z; acc[0][3] += ai.x * aj.w;
        acc[1][0] += ai.y * aj.x; acc[1][1] += ai.y * aj.y;
        acc[1][2] += ai.y * aj.z; acc[1][3] += ai.y * aj.w;
        acc[2][0] += ai.z * aj.x; acc[2][1] += ai.z * aj.y;
        acc[2][2] += ai.z * aj.z; acc[2][3] += ai.z * aj.w;
        acc[3][0] += ai.w * aj.x; acc[3][1] += ai.w * aj.y;
        acc[3][2] += ai.w * aj.z; acc[3][3] += ai.w * aj.w;
    }

    float* Gb = Gpart + ((size_t)(b * 128 + slice) * 64) * 64;
#pragma unroll
    for (int ii = 0; ii < 4; ii++)
        *(float4*)&Gb[(size_t)(i0 + ii) * 64 + j0] =
            make_float4(acc[ii][0], acc[ii][1], acc[ii][2], acc[ii][3]);
}

// ---------------------------------------------------------------------------
// K4b: reduce 128 gram partials + row softmax(max-A) via min-trick.
// grid 128 = b(2) x i(64), 64 threads. Writes transposed AcsT[b][j][i].
// ---------------------------------------------------------------------------
__global__ __launch_bounds__(64) void k_csoft(
    const float* __restrict__ Gpart, float* __restrict__ AcsT)
{
    int row = blockIdx.x;
    int b = row >> 6, i = row & 63;
    int j = threadIdx.x;

    const float* Gp = Gpart + ((size_t)(b * 128) * 64 + i) * 64 + j;
    float a = 0.f;
#pragma unroll 4
    for (int sl = 0; sl < 128; sl++)
        a += Gp[(size_t)sl * 4096];

    float mn = a;
    mn = fminf(mn, __shfl_xor(mn, 1));
    mn = fminf(mn, __shfl_xor(mn, 2));
    mn = fminf(mn, __shfl_xor(mn, 4));
    mn = fminf(mn, __shfl_xor(mn, 8));
    mn = fminf(mn, __shfl_xor(mn, 16));
    mn = fminf(mn, __shfl_xor(mn, 32));
    float p = __expf(mn - a);
    float s = p;
    s += __shfl_xor(s, 1);
    s += __shfl_xor(s, 2);
    s += __shfl_xor(s, 4);
    s += __shfl_xor(s, 8);
    s += __shfl_xor(s, 16);
    s += __shfl_xor(s, 32);
    AcsT[(size_t)b * 4096 + j * 64 + i] = p / s;
}

// ---------------------------------------------------------------------------
// K5: fused epilogue: sa_map = sg*(O0+O1)/(d0+d1) + sx ; f = sa_map +
// cg*ca + cx with ca = A^T-apply; out = oW @ f + ob.  All LDS-resident.
// grid 256 = b(2) x chunk(128: 32 px).
// ---------------------------------------------------------------------------
__global__ __launch_bounds__(256) void k_fuse_out(
    const float* __restrict__ Opart, const float* __restrict__ denp,
    const float* __restrict__ sx,    const float* __restrict__ cx,
    const float* __restrict__ AcsT,
    const float* __restrict__ oW,    const float* __restrict__ ob,
    const float* __restrict__ s_gamma, const float* __restrict__ c_gamma,
    float* __restrict__ out)
{
    __shared__ float A_sh[64][68];    // A[j][i]
    __shared__ float cxs[64][33];     // cx[j][px]
    __shared__ float f_sh[64][33];    // fused[c][px]
    __shared__ float oWT[64][68];     // oW^T[c][o]

    int bx = blockIdx.x;
    int b = bx >> 7, chunk = bx & 127;
    int px0 = chunk * 32;
    int t = threadIdx.x;
    float sgam = s_gamma[0], cgam = c_gamma[0];

    // A and oW^T staging (16 elems each per thread)
#pragma unroll
    for (int k = 0; k < 16; k++) {
        int idx = t + 256 * k;           // 4096
        int j = idx >> 6, i = idx & 63;
        A_sh[j][i] = AcsT[(size_t)b * 4096 + idx];
        oWT[j][i]  = oW[(size_t)i * 64 + j];   // [c=j][o=i]
    }
    // cx slab + f init = sg*(O0+O1)/(d0+d1) + sx + cx
#pragma unroll
    for (int k = 0; k < 8; k++) {
        int idx = t + 256 * k;           // 2048
        int c = idx >> 5, px = idx & 31;
        size_t o = (size_t)(b * 64 + c) * HW + px0 + px;
        float cv = cx[o];
        cxs[c][px] = cv;
        float d = denp[b * 4096 + px0 + px] + denp[8192 + b * 4096 + px0 + px];
        float O = Opart[((size_t)(b)*64 + c) * HW + px0 + px]
                + Opart[((size_t)(2 + b) * 64 + c) * HW + px0 + px];
        f_sh[c][px] = sgam * (O / d) + sx[o] + cv;
    }
    __syncthreads();

    // phase 1: ca[c][px] and f update
    {
        int px = t & 31, cg = t >> 5;
        int c0 = cg * 8;
        float ca[8] = {};
        for (int j = 0; j < 64; j++) {
            float xv = cxs[j][px];
            float4 a0 = *(const float4*)&A_sh[j][c0];
            float4 a1 = *(const float4*)&A_sh[j][c0 + 4];
            ca[0] += a0.x * xv; ca[1] += a0.y * xv;
            ca[2] += a0.z * xv; ca[3] += a0.w * xv;
            ca[4] += a1.x * xv; ca[5] += a1.y * xv;
            ca[6] += a1.z * xv; ca[7] += a1.w * xv;
        }
#pragma unroll
        for (int u = 0; u < 8; u++)
            f_sh[c0 + u][px] += cgam * ca[u];
    }
    __syncthreads();

    // phase 2: out = oW @ f + ob
    {
        int px = t & 31, og = t >> 5;
        int o0 = og * 8;
        float acc[8] = {};
        for (int c = 0; c < 64; c++) {
            float fv = f_sh[c][px];
            float4 a0 = *(const float4*)&oWT[c][o0];
            float4 a1 = *(const float4*)&oWT[c][o0 + 4];
            acc[0] += a0.x * fv; acc[1] += a0.y * fv;
            acc[2] += a0.z * fv; acc[3] += a0.w * fv;
            acc[4] += a1.x * fv; acc[5] += a1.y * fv;
            acc[6] += a1.z * fv; acc[7] += a1.w * fv;
        }
#pragma unroll
        for (int u = 0; u < 8; u++) {
            int o = o0 + u;
            out[(size_t)(b * 64 + o) * HW + px0 + px] = acc[u] + ob[o];
        }
    }
}

// ---------------------------------------------------------------------------
extern "C" void kernel_launch(void* const* d_in, const int* in_sizes, int n_in,
                              void* d_out, int out_size, void* d_ws, size_t ws_size,
                              hipStream_t stream)
{
    const float* x    = (const float*)d_in[0];
    const float* sW   = (const float*)d_in[1];
    const float* sb   = (const float*)d_in[2];
    const float* s_g  = (const float*)d_in[3];
    const float* s_b  = (const float*)d_in[4];
    const float* s_m  = (const float*)d_in[5];
    const float* s_v  = (const float*)d_in[6];
    const float* cW   = (const float*)d_in[7];
    const float* cb   = (const float*)d_in[8];
    const float* c_g  = (const float*)d_in[9];
    const float* c_b  = (const float*)d_in[10];
    const float* c_m  = (const float*)d_in[11];
    const float* c_v  = (const float*)d_in[12];
    const float* qW   = (const float*)d_in[13];
    const float* qb   = (const float*)d_in[14];
    const float* kW   = (const float*)d_in[15];
    const float* kb   = (const float*)d_in[16];
    const float* vW   = (const float*)d_in[17];
    const float* vb   = (const float*)d_in[18];
    const float* oW   = (const float*)d_in[19];
    const float* ob   = (const float*)d_in[20];
    const float* s_gamma = (const float*)d_in[21];
    const float* c_gamma = (const float*)d_in[22];

    float* ws    = (float*)d_ws;
    float* sx    = ws;                 // 524288
    float* cx    = ws + 524288;        // 524288
    float* Opart = ws + 1048576;       // 1048576  [jh2][b2][64][HW]
    float* denp  = ws + 2097152;       // 16384    [jh2][b2][HW]
    float* AcsT  = ws + 2113536;       // 8192
    float* Gpart = ws + 2121728;       // 1048576  [b2][128][64][64]
    float* scsh  = ws + 3170304;       // 256
    unsigned short* us = (unsigned short*)(ws + 3170560);
    unsigned short* qT = us;           // 65536  [B][HW][8]
    unsigned short* kT = us + 65536;   // 65536  [B][HW][8]
    unsigned short* vS = us + 131072;  // 524288 [B][64][HW] (swizzled)
    unsigned short* Wa = us + 655360;  // 73728  [2][9][64oc][64ic]

    k_wprep<<<18, 256, 0, stream>>>(sW, cW, sb, cb, s_g, s_b, s_m, s_v,
                                    c_g, c_b, c_m, c_v, Wa, scsh);
    k_conv3m<<<256, 256, 0, stream>>>(x, Wa, scsh, sx, cx);
    k_qkv<<<640, 64, 0, stream>>>(x, qW, qb, kW, kb, vW, vb, qT, kT, vS);
    k_gram2<<<256, 256, 0, stream>>>(cx, Gpart);
    k_csoft<<<128, 64, 0, stream>>>(Gpart, AcsT);
    k_attn_mfma<<<512, 256, 0, stream>>>(qT, kT, vS, Opart, denp);
    k_fuse_out<<<256, 256, 0, stream>>>(Opart, denp, sx, cx, AcsT,
                                        oW, ob, s_gamma, c_gamma, (float*)d_out);
}

// Round 6
// 170.884 us; speedup vs baseline: 2.4359x; 1.1292x over previous
//
#include <hip/hip_runtime.h>

#define HW 4096

typedef __attribute__((ext_vector_type(8)))  short short8;
typedef __attribute__((ext_vector_type(16))) float float16;

__device__ __forceinline__ unsigned short f2bf(float f) {
    unsigned u = __float_as_uint(f);
    u += 0x7fffu + ((u >> 16) & 1u);   // RNE
    return (unsigned short)(u >> 16);
}

// ---------------------------------------------------------------------------
// K0: weight prep. Wa[which][tap][oc][ic] bf16 + fused BN scale/shift.
// ---------------------------------------------------------------------------
__global__ __launch_bounds__(256) void k_wprep(
    const float* __restrict__ sW, const float* __restrict__ cW,
    const float* __restrict__ sb, const float* __restrict__ cb,
    const float* __restrict__ s_g, const float* __restrict__ s_b,
    const float* __restrict__ s_m, const float* __restrict__ s_v,
    const float* __restrict__ c_g, const float* __restrict__ c_b,
    const float* __restrict__ c_m, const float* __restrict__ c_v,
    unsigned short* __restrict__ Wa, float* __restrict__ scsh)
{
    int bx = blockIdx.x;
    int which = bx / 9, khw = bx % 9;
    const float* W = which ? cW : sW;
    int t = threadIdx.x;
#pragma unroll
    for (int i = 0; i < 16; i++) {
        int idx = t + 256 * i;            // 4096 = 64oc x 64ic
        int oc = idx >> 6, ic = idx & 63;
        float v = W[(size_t)(oc * 64 + ic) * 9 + khw];
        Wa[((size_t)(which * 9 + khw) * 64 + oc) * 64 + ic] = f2bf(v);
    }
    if (bx == 0 && t < 128) {
        int wh = t >> 6, oc = t & 63;
        const float* g  = wh ? c_g : s_g;
        const float* bb = wh ? c_b : s_b;
        const float* m  = wh ? c_m : s_m;
        const float* vv = wh ? c_v : s_v;
        const float* cbias = wh ? cb : sb;
        float scale = g[oc] * rsqrtf(vv[oc] + 1e-5f);
        scsh[wh * 128 + oc]      = scale;
        scsh[wh * 128 + 64 + oc] = (cbias[oc] - m[oc]) * scale + bb[oc];
    }
}

// ---------------------------------------------------------------------------
// KA: fused conv3x3(+BN+ReLU, MFMA implicit-GEMM) and 1x1 qkv projections.
// grid 416 = conv(256: which x b x row) + qkv(160: b x chunk x g).
// qkv outputs: qT/kT [b][hw][8] bf16; vB[b][hw>>4][c][sigma(hw&15)] bf16 --
// 16-j-blocked so the attention B-operand loads are fully coalesced.
// ---------------------------------------------------------------------------
__global__ __launch_bounds__(256) void k_conv_qkv(
    const float* __restrict__ x, const unsigned short* __restrict__ Wa,
    const float* __restrict__ scsh,
    const float* __restrict__ qW, const float* __restrict__ qb,
    const float* __restrict__ kW, const float* __restrict__ kb,
    const float* __restrict__ vW, const float* __restrict__ vb,
    float* __restrict__ sx, float* __restrict__ cx,
    unsigned short* __restrict__ qT, unsigned short* __restrict__ kT,
    unsigned short* __restrict__ vB)
{
    __shared__ unsigned short xs[3 * 8 * 66 * 8];
    int bx = blockIdx.x;
    int t = threadIdx.x;

    if (bx < 256) {
        // ---------------- conv role ----------------
        int which = bx >> 7;
        int b     = (bx >> 6) & 1;
        int row   = bx & 63;

        const float* xb = x + (size_t)(b * 64) * HW;
#pragma unroll
        for (int it = 0; it < 24; it++) {
            int idx = t + 256 * it;            // 6144 uint packs
            int lr  = idx >> 11;               // 0..2
            int rem = idx & 2047;
            int icp = rem >> 6;
            int col = rem & 63;
            int ir  = row - 1 + lr;
            unsigned pack = 0;
            if (ir >= 0 && ir < 64) {
                float v0 = xb[(size_t)(icp * 2)     * HW + ir * 64 + col];
                float v1 = xb[(size_t)(icp * 2 + 1) * HW + ir * 64 + col];
                pack = (unsigned)f2bf(v0) | ((unsigned)f2bf(v1) << 16);
            }
            int icg = icp >> 2, io = icp & 3;
            *(unsigned*)&xs[(((lr * 8 + icg) * 66 + col + 1) * 8) + io * 2] = pack;
        }
        if (t < 192) {                          // zero cols 0 and 65
            int pair = t & 3;
            int colsel = (t >> 2) & 1;
            int rg = t >> 3;                    // 0..23
            *(unsigned*)&xs[((rg * 66 + colsel * 65) * 8) + pair * 2] = 0u;
        }
        __syncthreads();

        int lane = t & 63, w = t >> 6;
        int l31 = lane & 31, half = lane >> 5;
        int colh = w & 1;
        int m0   = (w >> 1) * 32;
        int c    = colh * 32 + l31;

        float16 acc;
#pragma unroll
        for (int i = 0; i < 16; i++) acc[i] = 0.f;

        const unsigned short* Wbase =
            Wa + ((size_t)which * 9) * 4096 + (size_t)(m0 + l31) * 64 + half * 8;

#pragma unroll
        for (int khw = 0; khw < 9; khw++) {
            const int kh = khw / 3, kw = khw % 3;
#pragma unroll
            for (int icq = 0; icq < 4; icq++) {
                short8 af = *(const short8*)(Wbase + (size_t)khw * 4096 + icq * 16);
                const unsigned short* bp =
                    &xs[((kh * 8 + icq * 2 + half) * 66 + kw) * 8];
                short8 bf = *(const short8*)(bp + (size_t)c * 8);
                acc = __builtin_amdgcn_mfma_f32_32x32x16_bf16(af, bf, acc, 0, 0, 0);
            }
        }

        float* out = (which ? cx : sx) + (size_t)(b * 64) * HW;
        const float* sc = scsh + which * 128;
        int hwbase = row * 64 + c;
#pragma unroll
        for (int r = 0; r < 16; r++) {
            int oc = m0 + (r & 3) + 8 * (r >> 2) + 4 * half;
            float s  = sc[oc];
            float sh = sc[64 + oc];
            out[(size_t)oc * HW + hwbase] = fmaxf(acc[r] * s + sh, 0.f);
        }
    } else {
        // ---------------- qkv role ----------------
        int qbx = bx - 256;
        int b = qbx / 80, rem = qbx % 80;
        int chunk = rem / 5, g = rem % 5;
        int hw = chunk * 256 + t;
        const float* xb = x + (size_t)(b * 64) * HW + hw;

        float acc[16];
#pragma unroll
        for (int u = 0; u < 16; u++) acc[u] = 0.f;

        if (g == 0) {
            for (int ic = 0; ic < 64; ic++) {
                float xv = xb[ic * HW];
#pragma unroll
                for (int u = 0; u < 8; u++) acc[u]     += qW[u * 64 + ic] * xv;
#pragma unroll
                for (int u = 0; u < 8; u++) acc[8 + u] += kW[u * 64 + ic] * xv;
            }
            short8 qv, kv;
#pragma unroll
            for (int u = 0; u < 8; u++) qv[u] = (short)f2bf(acc[u] + qb[u]);
#pragma unroll
            for (int u = 0; u < 8; u++) kv[u] = (short)f2bf(acc[8 + u] + kb[u]);
            *(short8*)(qT + ((size_t)(b * HW) + hw) * 8) = qv;
            *(short8*)(kT + ((size_t)(b * HW) + hw) * 8) = kv;
        } else {
            int c0 = (g - 1) * 16;
            for (int ic = 0; ic < 64; ic++) {
                float xv = xb[ic * HW];
#pragma unroll
                for (int u = 0; u < 16; u++) acc[u] += vW[(c0 + u) * 64 + ic] * xv;
            }
            int m  = hw & 15;
            int sg = (m & 3) | ((m & 4) << 1) | ((m & 8) >> 1);   // sigma(m)
            size_t base = ((size_t)(b * 256) + (hw >> 4)) * 1024 + sg;
#pragma unroll
            for (int u = 0; u < 16; u++)
                vB[base + (size_t)(c0 + u) * 16] = f2bf(acc[u] + vb[c0 + u]);
        }
    }
}

// ---------------------------------------------------------------------------
// KB: fused spatial flash attention (bf16 MFMA, j-split x2, unnormalized
// partials) and channel-gram partials.
// grid 768 = attn(512: b x itile x jh) + gram(256: b x slice).
// ---------------------------------------------------------------------------
union SmemKB {
    struct { float o_sh[4][64][33]; float den_sh[4][32]; } a;
    float slab[32][68];
};

__global__ __launch_bounds__(256) void k_attn_gram(
    const unsigned short* __restrict__ qT, const unsigned short* __restrict__ kT,
    const unsigned short* __restrict__ vB, const float* __restrict__ cx,
    float* __restrict__ Opart, float* __restrict__ denp,
    float* __restrict__ Gpart)
{
    __shared__ SmemKB sm;
    int bx = blockIdx.x;
    int t = threadIdx.x;

    if (bx < 512) {
        // ---------------- attention role ----------------
        int lane = t & 63, w = t >> 6;
        int half = lane >> 5, l31 = lane & 31;
        int b  = bx >> 8;
        int itile = (bx >> 1) & 127;
        int jh = bx & 1;
        int i0 = itile * 32;

        short8 qf;
        if (half == 0) {
            qf = *(const short8*)(qT + ((size_t)(b * HW) + i0 + l31) * 8);
        } else {
#pragma unroll
            for (int i = 0; i < 8; i++) qf[i] = 0;
        }

        float16 o0, o1;
#pragma unroll
        for (int i = 0; i < 16; i++) { o0[i] = 0.f; o1[i] = 0.f; }
        float denr = 0.f;

        const unsigned short* kTb = kT + (size_t)(b * HW) * 8;
        const unsigned short* vBb = vB + (size_t)b * (256 * 1024);

        for (int tile = 0; tile < 16; tile++) {
            int j0 = jh * 2048 + w * 512 + tile * 32;
            int g0 = j0 >> 4;

            short8 kf;
            if (half == 0) {
                kf = *(const short8*)(kTb + (size_t)(j0 + l31) * 8);
            } else {
#pragma unroll
                for (int i = 0; i < 8; i++) kf[i] = 0;
            }

            float16 z;
#pragma unroll
            for (int i = 0; i < 16; i++) z[i] = 0.f;
            float16 s = __builtin_amdgcn_mfma_f32_32x32x16_bf16(kf, qf, z, 0, 0, 0);

            float p[16];
#pragma unroll
            for (int r = 0; r < 16; r++) {
                p[r] = __expf(s[r]);
                denr += p[r];
            }
            short8 pa0, pa1;
#pragma unroll
            for (int r = 0; r < 8; r++) {
                pa0[r] = (short)f2bf(p[r]);
                pa1[r] = (short)f2bf(p[8 + r]);
            }

            // coalesced V loads: [g][c][16] blocks
            const unsigned short* vg0 = vBb + (size_t)g0 * 1024 + half * 8;
            short8 v00 = *(const short8*)(vg0 + (size_t)l31 * 16);
            short8 v01 = *(const short8*)(vg0 + (size_t)(32 + l31) * 16);
            short8 v10 = *(const short8*)(vg0 + 1024 + (size_t)l31 * 16);
            short8 v11 = *(const short8*)(vg0 + 1024 + (size_t)(32 + l31) * 16);

            o0 = __builtin_amdgcn_mfma_f32_32x32x16_bf16(pa0, v00, o0, 0, 0, 0);
            o1 = __builtin_amdgcn_mfma_f32_32x32x16_bf16(pa0, v01, o1, 0, 0, 0);
            o0 = __builtin_amdgcn_mfma_f32_32x32x16_bf16(pa1, v10, o0, 0, 0, 0);
            o1 = __builtin_amdgcn_mfma_f32_32x32x16_bf16(pa1, v11, o1, 0, 0, 0);
        }

        float dfull = denr + __shfl_xor(denr, 32);
        if (half == 0) sm.a.den_sh[w][l31] = dfull;
#pragma unroll
        for (int r = 0; r < 16; r++) {
            int il = (r & 3) + 8 * (r >> 2) + 4 * half;
            sm.a.o_sh[w][l31][il]      = o0[r];
            sm.a.o_sh[w][32 + l31][il] = o1[r];
        }
        __syncthreads();

        int i  = t & 31;
        int cg = t >> 5;
        if (cg == 0)
            denp[jh * 8192 + b * 4096 + i0 + i] =
                sm.a.den_sh[0][i] + sm.a.den_sh[1][i] +
                sm.a.den_sh[2][i] + sm.a.den_sh[3][i];
#pragma unroll
        for (int u = 0; u < 8; u++) {
            int c = cg * 8 + u;
            float sv = sm.a.o_sh[0][c][i] + sm.a.o_sh[1][c][i]
                     + sm.a.o_sh[2][c][i] + sm.a.o_sh[3][c][i];
            Opart[((size_t)(jh * 2 + b) * 64 + c) * HW + i0 + i] = sv;
        }
    } else {
        // ---------------- gram role ----------------
        int gbx = bx - 512;
        int b = gbx >> 7, slice = gbx & 127;
        int hw0 = slice * 32;

#pragma unroll
        for (int it = 0; it < 2; it++) {
            int idx = t + 256 * it;          // 512 = hw(32) x cgroup(16)
            int hw = idx & 31, c0 = (idx >> 5) * 4;
            float4 vv;
            vv.x = cx[(size_t)(b * 64 + c0 + 0) * HW + hw0 + hw];
            vv.y = cx[(size_t)(b * 64 + c0 + 1) * HW + hw0 + hw];
            vv.z = cx[(size_t)(b * 64 + c0 + 2) * HW + hw0 + hw];
            vv.w = cx[(size_t)(b * 64 + c0 + 3) * HW + hw0 + hw];
            *(float4*)&sm.slab[hw][c0] = vv;
        }
        __syncthreads();

        int i0 = (t & 15) * 4, j0 = (t >> 4) * 4;
        float acc[4][4] = {};
#pragma unroll 8
        for (int hw = 0; hw < 32; hw++) {
            float4 ai = *(const float4*)&sm.slab[hw][i0];
            float4 aj = *(const float4*)&sm.slab[hw][j0];
            acc[0][0] += ai.x * aj.x; acc[0][1] += ai.x * aj.y;
            acc[0][2] += ai.x * aj.z; acc[0][3] += ai.x * aj.w;
            acc[1][0] += ai.y * aj.x; acc[1][1] += ai.y * aj.y;
            acc[1][2] += ai.y * aj.z; acc[1][3] += ai.y * aj.w;
            acc[2][0] += ai.z * aj.x; acc[2][1] += ai.z * aj.y;
            acc[2][2] += ai.z * aj.z; acc[2][3] += ai.z * aj.w;
            acc[3][0] += ai.w * aj.x; acc[3][1] += ai.w * aj.y;
            acc[3][2] += ai.w * aj.z; acc[3][3] += ai.w * aj.w;
        }

        float* Gb = Gpart + ((size_t)(b * 128 + slice) * 64) * 64;
#pragma unroll
        for (int ii = 0; ii < 4; ii++)
            *(float4*)&Gb[(size_t)(i0 + ii) * 64 + j0] =
                make_float4(acc[ii][0], acc[ii][1], acc[ii][2], acc[ii][3]);
    }
}

// ---------------------------------------------------------------------------
// K4b: reduce 128 gram partials + row softmax(max-A) via min-trick.
// grid 128 = b(2) x i(64), 64 threads. Writes transposed AcsT[b][j][i].
// ---------------------------------------------------------------------------
__global__ __launch_bounds__(64) void k_csoft(
    const float* __restrict__ Gpart, float* __restrict__ AcsT)
{
    int row = blockIdx.x;
    int b = row >> 6, i = row & 63;
    int j = threadIdx.x;

    const float* Gp = Gpart + ((size_t)(b * 128) * 64 + i) * 64 + j;
    float a = 0.f;
#pragma unroll 4
    for (int sl = 0; sl < 128; sl++)
        a += Gp[(size_t)sl * 4096];

    float mn = a;
    mn = fminf(mn, __shfl_xor(mn, 1));
    mn = fminf(mn, __shfl_xor(mn, 2));
    mn = fminf(mn, __shfl_xor(mn, 4));
    mn = fminf(mn, __shfl_xor(mn, 8));
    mn = fminf(mn, __shfl_xor(mn, 16));
    mn = fminf(mn, __shfl_xor(mn, 32));
    float p = __expf(mn - a);
    float s = p;
    s += __shfl_xor(s, 1);
    s += __shfl_xor(s, 2);
    s += __shfl_xor(s, 4);
    s += __shfl_xor(s, 8);
    s += __shfl_xor(s, 16);
    s += __shfl_xor(s, 32);
    AcsT[(size_t)b * 4096 + j * 64 + i] = p / s;
}

// ---------------------------------------------------------------------------
// K5: fused epilogue: sa_map = sg*(O0+O1)/(d0+d1) + sx ; f = sa_map +
// cg*ca + cx with ca = A^T-apply; out = oW @ f + ob.  All LDS-resident.
// grid 256 = b(2) x chunk(128: 32 px).
// ---------------------------------------------------------------------------
__global__ __launch_bounds__(256) void k_fuse_out(
    const float* __restrict__ Opart, const float* __restrict__ denp,
    const float* __restrict__ sx,    const float* __restrict__ cx,
    const float* __restrict__ AcsT,
    const float* __restrict__ oW,    const float* __restrict__ ob,
    const float* __restrict__ s_gamma, const float* __restrict__ c_gamma,
    float* __restrict__ out)
{
    __shared__ float A_sh[64][68];    // A[j][i]
    __shared__ float cxs[64][33];     // cx[j][px]
    __shared__ float f_sh[64][33];    // fused[c][px]
    __shared__ float oWT[64][68];     // oW^T[c][o]

    int bx = blockIdx.x;
    int b = bx >> 7, chunk = bx & 127;
    int px0 = chunk * 32;
    int t = threadIdx.x;
    float sgam = s_gamma[0], cgam = c_gamma[0];

#pragma unroll
    for (int k = 0; k < 16; k++) {
        int idx = t + 256 * k;           // 4096
        int j = idx >> 6, i = idx & 63;
        A_sh[j][i] = AcsT[(size_t)b * 4096 + idx];
        oWT[j][i]  = oW[(size_t)i * 64 + j];   // [c=j][o=i]
    }
#pragma unroll
    for (int k = 0; k < 8; k++) {
        int idx = t + 256 * k;           // 2048
        int c = idx >> 5, px = idx & 31;
        size_t o = (size_t)(b * 64 + c) * HW + px0 + px;
        float cv = cx[o];
        cxs[c][px] = cv;
        float d = denp[b * 4096 + px0 + px] + denp[8192 + b * 4096 + px0 + px];
        float O = Opart[((size_t)(b)*64 + c) * HW + px0 + px]
                + Opart[((size_t)(2 + b) * 64 + c) * HW + px0 + px];
        f_sh[c][px] = sgam * (O / d) + sx[o] + cv;
    }
    __syncthreads();

    {
        int px = t & 31, cg = t >> 5;
        int c0 = cg * 8;
        float ca[8] = {};
        for (int j = 0; j < 64; j++) {
            float xv = cxs[j][px];
            float4 a0 = *(const float4*)&A_sh[j][c0];
            float4 a1 = *(const float4*)&A_sh[j][c0 + 4];
            ca[0] += a0.x * xv; ca[1] += a0.y * xv;
            ca[2] += a0.z * xv; ca[3] += a0.w * xv;
            ca[4] += a1.x * xv; ca[5] += a1.y * xv;
            ca[6] += a1.z * xv; ca[7] += a1.w * xv;
        }
#pragma unroll
        for (int u = 0; u < 8; u++)
            f_sh[c0 + u][px] += cgam * ca[u];
    }
    __syncthreads();

    {
        int px = t & 31, og = t >> 5;
        int o0 = og * 8;
        float acc[8] = {};
        for (int c = 0; c < 64; c++) {
            float fv = f_sh[c][px];
            float4 a0 = *(const float4*)&oWT[c][o0];
            float4 a1 = *(const float4*)&oWT[c][o0 + 4];
            acc[0] += a0.x * fv; acc[1] += a0.y * fv;
            acc[2] += a0.z * fv; acc[3] += a0.w * fv;
            acc[4] += a1.x * fv; acc[5] += a1.y * fv;
            acc[6] += a1.z * fv; acc[7] += a1.w * fv;
        }
#pragma unroll
        for (int u = 0; u < 8; u++) {
            int o = o0 + u;
            out[(size_t)(b * 64 + o) * HW + px0 + px] = acc[u] + ob[o];
        }
    }
}

// ---------------------------------------------------------------------------
extern "C" void kernel_launch(void* const* d_in, const int* in_sizes, int n_in,
                              void* d_out, int out_size, void* d_ws, size_t ws_size,
                              hipStream_t stream)
{
    const float* x    = (const float*)d_in[0];
    const float* sW   = (const float*)d_in[1];
    const float* sb   = (const float*)d_in[2];
    const float* s_g  = (const float*)d_in[3];
    const float* s_b  = (const float*)d_in[4];
    const float* s_m  = (const float*)d_in[5];
    const float* s_v  = (const float*)d_in[6];
    const float* cW   = (const float*)d_in[7];
    const float* cb   = (const float*)d_in[8];
    const float* c_g  = (const float*)d_in[9];
    const float* c_b  = (const float*)d_in[10];
    const float* c_m  = (const float*)d_in[11];
    const float* c_v  = (const float*)d_in[12];
    const float* qW   = (const float*)d_in[13];
    const float* qb   = (const float*)d_in[14];
    const float* kW   = (const float*)d_in[15];
    const float* kb   = (const float*)d_in[16];
    const float* vW   = (const float*)d_in[17];
    const float* vb   = (const float*)d_in[18];
    const float* oW   = (const float*)d_in[19];
    const float* ob   = (const float*)d_in[20];
    const float* s_gamma = (const float*)d_in[21];
    const float* c_gamma = (const float*)d_in[22];

    float* ws    = (float*)d_ws;
    float* sx    = ws;                 // 524288
    float* cx    = ws + 524288;        // 524288
    float* Opart = ws + 1048576;       // 1048576  [jh2][b2][64][HW]
    float* denp  = ws + 2097152;       // 16384    [jh2][b2][HW]
    float* AcsT  = ws + 2113536;       // 8192
    float* Gpart = ws + 2121728;       // 1048576  [b2][128][64][64]
    float* scsh  = ws + 3170304;       // 256
    unsigned short* us = (unsigned short*)(ws + 3170560);
    unsigned short* qT = us;           // 65536  [B][HW][8]
    unsigned short* kT = us + 65536;   // 65536  [B][HW][8]
    unsigned short* vB = us + 131072;  // 524288 [B][256][64][16] (j-blocked)
    unsigned short* Wa = us + 655360;  // 73728  [2][9][64oc][64ic]

    k_wprep<<<18, 256, 0, stream>>>(sW, cW, sb, cb, s_g, s_b, s_m, s_v,
                                    c_g, c_b, c_m, c_v, Wa, scsh);
    k_conv_qkv<<<416, 256, 0, stream>>>(x, Wa, scsh, qW, qb, kW, kb, vW, vb,
                                        sx, cx, qT, kT, vB);
    k_attn_gram<<<768, 256, 0, stream>>>(qT, kT, vB, cx, Opart, denp, Gpart);
    k_csoft<<<128, 64, 0, stream>>>(Gpart, AcsT);
    k_fuse_out<<<256, 256, 0, stream>>>(Opart, denp, sx, cx, AcsT,
                                        oW, ob, s_gamma, c_gamma, (float*)d_out);
}